// Round 1
// baseline (844.546 us; speedup 1.0000x reference)
//
#include <hip/hip_runtime.h>
#include <math.h>

#define D   128
#define HH  4
#define HD  32
#define NB  8
#define HID 512

// ---------- helpers ----------

// monotone float <-> ordered-uint map for atomicMax on floats
__device__ __forceinline__ unsigned f2o(float f) {
    unsigned u = __float_as_uint(f);
    return (u & 0x80000000u) ? ~u : (u | 0x80000000u);
}
__device__ __forceinline__ float o2f(unsigned e) {
    return (e & 0x80000000u) ? __uint_as_float(e ^ 0x80000000u)
                             : __uint_as_float(~e);
}

__device__ __forceinline__ float gelu_tanh(float x) {
    float x3 = x * x * x;
    float u = 0.7978845608028654f * (x + 0.044715f * x3);
    return 0.5f * x * (1.0f + tanhf(u));
}

// ---------- K0: init workspace (ws is poisoned 0xAA every call) ----------
__global__ void k0_init(float* __restrict__ agg, unsigned* __restrict__ segmax,
                        float* __restrict__ segsum, int N) {
    int i = blockIdx.x * blockDim.x + threadIdx.x;
    if (i < N * D) agg[i] = 0.0f;
    if (i < N * HH) { segmax[i] = 0x007FFFFFu; /* f2o(-inf) */ segsum[i] = 0.0f; }
}

// ---------- K1: q,k,v = x@W + b  (8 nodes per block, 128 threads) ----------
__global__ void k1_qkv(const float* __restrict__ x,
                       const float* __restrict__ Wq, const float* __restrict__ bq,
                       const float* __restrict__ Wk, const float* __restrict__ bk,
                       const float* __restrict__ Wv, const float* __restrict__ bv,
                       float* __restrict__ q, float* __restrict__ k, float* __restrict__ v,
                       int N) {
    __shared__ float xs[D * NB];          // transposed: xs[kk*NB + j]
    int n0 = blockIdx.x * NB;
    int t  = threadIdx.x;                 // output column 0..127
    #pragma unroll
    for (int j = 0; j < NB; ++j) {
        int n = n0 + j;
        xs[t * NB + j] = (n < N) ? x[(size_t)n * D + t] : 0.0f;
    }
    __syncthreads();

    float aq[NB], ak[NB], av[NB];
    float bqv = bq[t], bkv = bk[t], bvv = bv[t];
    #pragma unroll
    for (int j = 0; j < NB; ++j) { aq[j] = bqv; ak[j] = bkv; av[j] = bvv; }

    #pragma unroll 4
    for (int kk = 0; kk < D; ++kk) {
        float wq = Wq[kk * D + t], wk = Wk[kk * D + t], wv = Wv[kk * D + t];
        float4 xa = *(const float4*)(xs + kk * NB);
        float4 xb = *(const float4*)(xs + kk * NB + 4);
        float xv[NB] = {xa.x, xa.y, xa.z, xa.w, xb.x, xb.y, xb.z, xb.w};
        #pragma unroll
        for (int j = 0; j < NB; ++j) {
            aq[j] = fmaf(xv[j], wq, aq[j]);
            ak[j] = fmaf(xv[j], wk, ak[j]);
            av[j] = fmaf(xv[j], wv, av[j]);
        }
    }
    #pragma unroll
    for (int j = 0; j < NB; ++j) {
        int n = n0 + j;
        if (n < N) {
            q[(size_t)n * D + t] = aq[j];
            k[(size_t)n * D + t] = ak[j];
            v[(size_t)n * D + t] = av[j];
        }
    }
}

// ---------- K2: per-edge scores + segment max ----------
__global__ void k2_scores(const float* __restrict__ q, const float* __restrict__ k,
                          const int* __restrict__ src, const int* __restrict__ dst,
                          float* __restrict__ sc_out, unsigned* __restrict__ segmax,
                          int E) {
    int gid = blockIdx.x * blockDim.x + threadIdx.x;
    if (gid >= E * HH) return;
    int e = gid >> 2, h = gid & 3;
    int s = src[e], d = dst[e];
    const float4* qp = (const float4*)(q + (size_t)d * D + h * HD);
    const float4* kp = (const float4*)(k + (size_t)s * D + h * HD);
    float acc = 0.f;
    #pragma unroll
    for (int i = 0; i < HD / 4; ++i) {
        float4 a = qp[i], b = kp[i];
        acc += a.x * b.x + a.y * b.y + a.z * b.z + a.w * b.w;
    }
    acc *= 0.17677669529663687f;   // 32^-0.5
    sc_out[gid] = acc;
    atomicMax(&segmax[d * HH + h], f2o(acc));
}

// ---------- K3: ex = exp(s - max), segment sum ----------
__global__ void k3_expsum(float* __restrict__ sc, const unsigned* __restrict__ segmax,
                          float* __restrict__ segsum, const int* __restrict__ dst,
                          int E) {
    int gid = blockIdx.x * blockDim.x + threadIdx.x;
    if (gid >= E * HH) return;
    int e = gid >> 2, h = gid & 3;
    int d = dst[e];
    float m  = o2f(segmax[d * HH + h]);
    float ex = expf(sc[gid] - m);
    sc[gid] = ex;
    atomicAdd(&segsum[d * HH + h], ex);
}

// ---------- K4: aggregated += ex * v[src]   (normalization deferred to K5) ----------
__global__ void k4_agg(const float* __restrict__ ex, const float* __restrict__ v,
                       const int* __restrict__ src, const int* __restrict__ dst,
                       float* __restrict__ agg, int E) {
    int e = blockIdx.x * 2 + (threadIdx.x >> 7);
    if (e >= E) return;
    int t = threadIdx.x & 127;
    int s = src[e], d = dst[e];
    int h = t >> 5;
    float w = ex[e * HH + h];
    float val = w * v[(size_t)s * D + t];
    atomicAdd(&agg[(size_t)d * D + t], val);
}

// ---------- K5: out = LN(agg/segsum @ Wo + bo + residual) ----------
__global__ void k5_wo_ln(const float* __restrict__ agg, const float* __restrict__ segsum,
                         const float* __restrict__ Wo, const float* __restrict__ bo,
                         const float* __restrict__ x, const float* __restrict__ g,
                         const float* __restrict__ b, float* __restrict__ lnout, int N) {
    __shared__ float xs[D * NB];          // transposed agg tile, then reused as row tile
    __shared__ float ps[NB * 16], ps2[NB * 16];
    __shared__ float mu[NB], rstd[NB];
    int n0 = blockIdx.x * NB;
    int t  = threadIdx.x;
    int h  = t >> 5;
    #pragma unroll
    for (int j = 0; j < NB; ++j) {
        int n = n0 + j;
        float a = 0.f;
        if (n < N) {
            float ssum = segsum[n * HH + h];
            a = agg[(size_t)n * D + t];
            a = (ssum > 0.f) ? a / ssum : 0.f;
        }
        xs[t * NB + j] = a;
    }
    __syncthreads();

    float acc[NB];
    float bov = bo[t];
    #pragma unroll
    for (int j = 0; j < NB; ++j) acc[j] = bov;

    #pragma unroll 4
    for (int kk = 0; kk < D; ++kk) {
        float w = Wo[kk * D + t];
        float4 xa = *(const float4*)(xs + kk * NB);
        float4 xb = *(const float4*)(xs + kk * NB + 4);
        float xv[NB] = {xa.x, xa.y, xa.z, xa.w, xb.x, xb.y, xb.z, xb.w};
        #pragma unroll
        for (int j = 0; j < NB; ++j) acc[j] = fmaf(xv[j], w, acc[j]);
    }
    // residual
    #pragma unroll
    for (int j = 0; j < NB; ++j) {
        int n = n0 + j;
        if (n < N) acc[j] += x[(size_t)n * D + t];
    }
    __syncthreads();            // done reading xs as transposed tile
    #pragma unroll
    for (int j = 0; j < NB; ++j) xs[j * D + t] = acc[j];   // row tile [n][c]
    __syncthreads();

    int nn = t >> 4, lane = t & 15;     // 16 threads per node
    float s1 = 0.f, s2 = 0.f;
    #pragma unroll
    for (int c = lane; c < D; c += 16) {
        float vv = xs[nn * D + c];
        s1 += vv; s2 += vv * vv;
    }
    ps[t] = s1; ps2[t] = s2;
    __syncthreads();
    if (t < NB) {
        float m = 0.f, m2 = 0.f;
        #pragma unroll
        for (int i = 0; i < 16; ++i) { m += ps[t * 16 + i]; m2 += ps2[t * 16 + i]; }
        m *= (1.0f / D); m2 *= (1.0f / D);
        float var = m2 - m * m;
        mu[t] = m; rstd[t] = rsqrtf(var + 1e-5f);
    }
    __syncthreads();
    float gv = g[t], bv = b[t];
    #pragma unroll
    for (int j = 0; j < NB; ++j) {
        int n = n0 + j;
        if (n < N) lnout[(size_t)n * D + t] = (acc[j] - mu[j]) * rstd[j] * gv + bv;
    }
}

// ---------- K6: final = ln + gelu(ln@W1+b1)@W2+b2 ----------
__global__ void k6_mlp(const float* __restrict__ ln, const float* __restrict__ W1,
                       const float* __restrict__ b1, const float* __restrict__ W2,
                       const float* __restrict__ b2, float* __restrict__ out, int N) {
    __shared__ float xs[D * NB];          // transposed ln tile  [kk*NB+j]   4 KB
    __shared__ float hid[NB * HID];       // hidden tile [n][c]             16 KB
    int n0 = blockIdx.x * NB;
    int t  = threadIdx.x;
    #pragma unroll
    for (int j = 0; j < NB; ++j) {
        int n = n0 + j;
        xs[t * NB + j] = (n < N) ? ln[(size_t)n * D + t] : 0.0f;
    }
    __syncthreads();

    // phase 1: hidden = gelu(ln @ W1 + b1); thread t owns cols t, t+128, t+256, t+384
    float acc1[4][NB];
    #pragma unroll
    for (int c = 0; c < 4; ++c) {
        float bb = b1[t + 128 * c];
        #pragma unroll
        for (int j = 0; j < NB; ++j) acc1[c][j] = bb;
    }
    #pragma unroll 2
    for (int kk = 0; kk < D; ++kk) {
        float4 xa = *(const float4*)(xs + kk * NB);
        float4 xb = *(const float4*)(xs + kk * NB + 4);
        float xv[NB] = {xa.x, xa.y, xa.z, xa.w, xb.x, xb.y, xb.z, xb.w};
        float w0 = W1[kk * HID + t];
        float w1 = W1[kk * HID + t + 128];
        float w2 = W1[kk * HID + t + 256];
        float w3 = W1[kk * HID + t + 384];
        #pragma unroll
        for (int j = 0; j < NB; ++j) {
            acc1[0][j] = fmaf(xv[j], w0, acc1[0][j]);
            acc1[1][j] = fmaf(xv[j], w1, acc1[1][j]);
            acc1[2][j] = fmaf(xv[j], w2, acc1[2][j]);
            acc1[3][j] = fmaf(xv[j], w3, acc1[3][j]);
        }
    }
    #pragma unroll
    for (int c = 0; c < 4; ++c)
        #pragma unroll
        for (int j = 0; j < NB; ++j)
            hid[j * HID + t + 128 * c] = gelu_tanh(acc1[c][j]);
    __syncthreads();

    // phase 2: out = hid @ W2 + b2; thread t owns col t for all 8 nodes
    float acc2[NB];
    float b2v = b2[t];
    #pragma unroll
    for (int j = 0; j < NB; ++j) acc2[j] = b2v;
    for (int kk = 0; kk < HID; kk += 4) {
        float w0 = W2[(kk + 0) * D + t];
        float w1 = W2[(kk + 1) * D + t];
        float w2 = W2[(kk + 2) * D + t];
        float w3 = W2[(kk + 3) * D + t];
        #pragma unroll
        for (int j = 0; j < NB; ++j) {
            float4 hv = *(const float4*)(hid + j * HID + kk);
            acc2[j] += hv.x * w0 + hv.y * w1 + hv.z * w2 + hv.w * w3;
        }
    }
    #pragma unroll
    for (int j = 0; j < NB; ++j) {
        int n = n0 + j;
        if (n < N) out[(size_t)n * D + t] = xs[t * NB + j] + acc2[j];
    }
}

// ---------- launch ----------
extern "C" void kernel_launch(void* const* d_in, const int* in_sizes, int n_in,
                              void* d_out, int out_size, void* d_ws, size_t ws_size,
                              hipStream_t stream) {
    const float* x   = (const float*)d_in[0];
    const int*   ei  = (const int*)d_in[1];
    const float* Wq  = (const float*)d_in[2];
    const float* bq  = (const float*)d_in[3];
    const float* Wk  = (const float*)d_in[4];
    const float* bk  = (const float*)d_in[5];
    const float* Wv  = (const float*)d_in[6];
    const float* bv  = (const float*)d_in[7];
    const float* Wo  = (const float*)d_in[8];
    const float* bo  = (const float*)d_in[9];
    const float* lng = (const float*)d_in[10];
    const float* lnb = (const float*)d_in[11];
    const float* W1  = (const float*)d_in[12];
    const float* b1  = (const float*)d_in[13];
    const float* W2  = (const float*)d_in[14];
    const float* b2  = (const float*)d_in[15];
    float* out = (float*)d_out;

    int N = in_sizes[0] / D;
    int E = in_sizes[1] / 2;
    const int* srcp = ei;
    const int* dstp = ei + E;

    // workspace layout (floats)
    float*    q      = (float*)d_ws;
    float*    k      = q + (size_t)N * D;
    float*    v      = k + (size_t)N * D;
    float*    agg    = v + (size_t)N * D;
    float*    ex     = agg + (size_t)N * D;            // E*HH
    unsigned* segmax = (unsigned*)(ex + (size_t)E * HH);
    float*    segsum = (float*)(segmax + (size_t)N * HH);
    float*    lnout  = segsum + (size_t)N * HH;

    int nblk = (N + NB - 1) / NB;

    k0_init<<<(N * D + 255) / 256, 256, 0, stream>>>(agg, segmax, segsum, N);
    k1_qkv<<<nblk, D, 0, stream>>>(x, Wq, bq, Wk, bk, Wv, bv, q, k, v, N);
    k2_scores<<<(E * HH + 255) / 256, 256, 0, stream>>>(q, k, srcp, dstp, ex, segmax, E);
    k3_expsum<<<(E * HH + 255) / 256, 256, 0, stream>>>(ex, segmax, segsum, dstp, E);
    k4_agg<<<(E + 1) / 2, 256, 0, stream>>>(ex, v, srcp, dstp, agg, E);
    k5_wo_ln<<<nblk, D, 0, stream>>>(agg, segsum, Wo, bo, x, lng, lnb, lnout, N);
    k6_mlp<<<nblk, D, 0, stream>>>(lnout, W1, b1, W2, b2, out, N);
}

// Round 2
// 698.768 us; speedup vs baseline: 1.2086x; 1.2086x over previous
//
#include <hip/hip_runtime.h>
#include <math.h>

#define D   128
#define HH  4
#define HD  32
#define NB  8
#define HID 512
#define WPB 4     // nodes (waves) per block in fused attention

__device__ __forceinline__ float gelu_tanh(float x) {
    float x3 = x * x * x;
    float u = 0.7978845608028654f * (x + 0.044715f * x3);
    return 0.5f * x * (1.0f + tanhf(u));
}

// ---------- K0: zero degree array (ws poisoned 0xAA each call) ----------
__global__ void k0_zero_deg(int* __restrict__ deg, int N) {
    int i = blockIdx.x * blockDim.x + threadIdx.x;
    if (i < N) deg[i] = 0;
}

// ---------- K1: q,k,v = x@W + b  (8 nodes per block, 128 threads) ----------
__global__ void k1_qkv(const float* __restrict__ x,
                       const float* __restrict__ Wq, const float* __restrict__ bq,
                       const float* __restrict__ Wk, const float* __restrict__ bk,
                       const float* __restrict__ Wv, const float* __restrict__ bv,
                       float* __restrict__ q, float* __restrict__ k, float* __restrict__ v,
                       int N) {
    __shared__ float xs[D * NB];          // transposed: xs[kk*NB + j]
    int n0 = blockIdx.x * NB;
    int t  = threadIdx.x;                 // output column 0..127
    #pragma unroll
    for (int j = 0; j < NB; ++j) {
        int n = n0 + j;
        xs[t * NB + j] = (n < N) ? x[(size_t)n * D + t] : 0.0f;
    }
    __syncthreads();

    float aq[NB], ak[NB], av[NB];
    float bqv = bq[t], bkv = bk[t], bvv = bv[t];
    #pragma unroll
    for (int j = 0; j < NB; ++j) { aq[j] = bqv; ak[j] = bkv; av[j] = bvv; }

    #pragma unroll 4
    for (int kk = 0; kk < D; ++kk) {
        float wq = Wq[kk * D + t], wk = Wk[kk * D + t], wv = Wv[kk * D + t];
        float4 xa = *(const float4*)(xs + kk * NB);
        float4 xb = *(const float4*)(xs + kk * NB + 4);
        float xv[NB] = {xa.x, xa.y, xa.z, xa.w, xb.x, xb.y, xb.z, xb.w};
        #pragma unroll
        for (int j = 0; j < NB; ++j) {
            aq[j] = fmaf(xv[j], wq, aq[j]);
            ak[j] = fmaf(xv[j], wk, ak[j]);
            av[j] = fmaf(xv[j], wv, av[j]);
        }
    }
    #pragma unroll
    for (int j = 0; j < NB; ++j) {
        int n = n0 + j;
        if (n < N) {
            q[(size_t)n * D + t] = aq[j];
            k[(size_t)n * D + t] = ak[j];
            v[(size_t)n * D + t] = av[j];
        }
    }
}

// ---------- CSR build ----------
__global__ void k_hist(const int* __restrict__ dst, int* __restrict__ deg, int E) {
    int i = blockIdx.x * blockDim.x + threadIdx.x;
    if (i < E) atomicAdd(&deg[dst[i]], 1);
}

// single-block exclusive scan of deg[0..N) -> row_ptr[0..N], cursor copy
__global__ void k_scan(const int* __restrict__ deg, int* __restrict__ row_ptr,
                       int* __restrict__ cursor, int N) {
    __shared__ int sums[1024];
    int t = threadIdx.x;
    int CH = (N + 1023) / 1024;
    int lo = t * CH, hi = min(lo + CH, N);
    int s = 0;
    for (int i = lo; i < hi; ++i) s += deg[i];
    sums[t] = s;
    __syncthreads();
    for (int off = 1; off < 1024; off <<= 1) {
        int vv = (t >= off) ? sums[t - off] : 0;
        __syncthreads();
        sums[t] += vv;
        __syncthreads();
    }
    int base = (t == 0) ? 0 : sums[t - 1];
    for (int i = lo; i < hi; ++i) {
        row_ptr[i] = base;
        cursor[i]  = base;
        base += deg[i];
    }
    if (t == 0) row_ptr[N] = sums[1023];
}

__global__ void k_scatter(const int* __restrict__ src, const int* __restrict__ dst,
                          int* __restrict__ cursor, int* __restrict__ col, int E) {
    int i = blockIdx.x * blockDim.x + threadIdx.x;
    if (i < E) {
        int d = dst[i];
        int pos = atomicAdd(&cursor[d], 1);
        col[pos] = src[i];
    }
}

// ---------- fused attention: scores + online softmax + aggregate ----------
// one wave per dst node; lane l owns dims {2l, 2l+1}; head = l>>4.
__global__ void k_attn(const float* __restrict__ q, const float* __restrict__ k,
                       const float* __restrict__ v, const int* __restrict__ row_ptr,
                       const int* __restrict__ col, float* __restrict__ agg, int N) {
    int wave = threadIdx.x >> 6;
    int lane = threadIdx.x & 63;
    int n = blockIdx.x * WPB + wave;
    if (n >= N) return;
    int beg = row_ptr[n], end = row_ptr[n + 1];

    float2 qv = *(const float2*)(q + (size_t)n * D + 2 * lane);

    float m = -INFINITY, l = 0.f;
    float2 acc = {0.f, 0.f};

    float2 kv, vv;
    if (beg < end) {
        int s0 = col[beg];
        kv = *(const float2*)(k + (size_t)s0 * D + 2 * lane);
        vv = *(const float2*)(v + (size_t)s0 * D + 2 * lane);
    }
    for (int p = beg; p < end; ++p) {
        float2 ck = kv, cv = vv;
        if (p + 1 < end) {                      // prefetch next edge
            int s1 = col[p + 1];
            kv = *(const float2*)(k + (size_t)s1 * D + 2 * lane);
            vv = *(const float2*)(v + (size_t)s1 * D + 2 * lane);
        }
        float part = qv.x * ck.x + qv.y * ck.y;
        part += __shfl_xor(part, 1);
        part += __shfl_xor(part, 2);
        part += __shfl_xor(part, 4);
        part += __shfl_xor(part, 8);            // 16-lane head reduction
        float sc = part * 0.17677669529663687f; // 32^-0.5
        float mn = fmaxf(m, sc);
        float alpha = __expf(m - mn);           // first iter: exp(-inf)=0
        float pe    = __expf(sc - mn);
        l = l * alpha + pe;
        acc.x = acc.x * alpha + pe * cv.x;
        acc.y = acc.y * alpha + pe * cv.y;
        m = mn;
    }
    float inv = (l > 0.f) ? 1.f / l : 0.f;      // deg==0 -> aggregated = 0
    float2 o = {acc.x * inv, acc.y * inv};
    *(float2*)(agg + (size_t)n * D + 2 * lane) = o;
}

// ---------- K5: out = LN(agg @ Wo + bo + residual)  (agg pre-normalized) ----------
__global__ void k5_wo_ln(const float* __restrict__ agg,
                         const float* __restrict__ Wo, const float* __restrict__ bo,
                         const float* __restrict__ x, const float* __restrict__ g,
                         const float* __restrict__ b, float* __restrict__ lnout, int N) {
    __shared__ float xs[D * NB];
    __shared__ float ps[NB * 16], ps2[NB * 16];
    __shared__ float mu[NB], rstd[NB];
    int n0 = blockIdx.x * NB;
    int t  = threadIdx.x;
    #pragma unroll
    for (int j = 0; j < NB; ++j) {
        int n = n0 + j;
        xs[t * NB + j] = (n < N) ? agg[(size_t)n * D + t] : 0.0f;
    }
    __syncthreads();

    float acc[NB];
    float bov = bo[t];
    #pragma unroll
    for (int j = 0; j < NB; ++j) acc[j] = bov;

    #pragma unroll 4
    for (int kk = 0; kk < D; ++kk) {
        float w = Wo[kk * D + t];
        float4 xa = *(const float4*)(xs + kk * NB);
        float4 xb = *(const float4*)(xs + kk * NB + 4);
        float xv[NB] = {xa.x, xa.y, xa.z, xa.w, xb.x, xb.y, xb.z, xb.w};
        #pragma unroll
        for (int j = 0; j < NB; ++j) acc[j] = fmaf(xv[j], w, acc[j]);
    }
    #pragma unroll
    for (int j = 0; j < NB; ++j) {
        int n = n0 + j;
        if (n < N) acc[j] += x[(size_t)n * D + t];
    }
    __syncthreads();
    #pragma unroll
    for (int j = 0; j < NB; ++j) xs[j * D + t] = acc[j];
    __syncthreads();

    int nn = t >> 4, lane = t & 15;
    float s1 = 0.f, s2 = 0.f;
    #pragma unroll
    for (int c = lane; c < D; c += 16) {
        float vvv = xs[nn * D + c];
        s1 += vvv; s2 += vvv * vvv;
    }
    ps[t] = s1; ps2[t] = s2;
    __syncthreads();
    if (t < NB) {
        float mm = 0.f, m2 = 0.f;
        #pragma unroll
        for (int i = 0; i < 16; ++i) { mm += ps[t * 16 + i]; m2 += ps2[t * 16 + i]; }
        mm *= (1.0f / D); m2 *= (1.0f / D);
        float var = m2 - mm * mm;
        mu[t] = mm; rstd[t] = rsqrtf(var + 1e-5f);
    }
    __syncthreads();
    float gv = g[t], bv = b[t];
    #pragma unroll
    for (int j = 0; j < NB; ++j) {
        int n = n0 + j;
        if (n < N) lnout[(size_t)n * D + t] = (acc[j] - mu[j]) * rstd[j] * gv + bv;
    }
}

// ---------- K6: final = ln + gelu(ln@W1+b1)@W2+b2 ----------
__global__ void k6_mlp(const float* __restrict__ ln, const float* __restrict__ W1,
                       const float* __restrict__ b1, const float* __restrict__ W2,
                       const float* __restrict__ b2, float* __restrict__ out, int N) {
    __shared__ float xs[D * NB];
    __shared__ float hid[NB * HID];
    int n0 = blockIdx.x * NB;
    int t  = threadIdx.x;
    #pragma unroll
    for (int j = 0; j < NB; ++j) {
        int n = n0 + j;
        xs[t * NB + j] = (n < N) ? ln[(size_t)n * D + t] : 0.0f;
    }
    __syncthreads();

    float acc1[4][NB];
    #pragma unroll
    for (int c = 0; c < 4; ++c) {
        float bb = b1[t + 128 * c];
        #pragma unroll
        for (int j = 0; j < NB; ++j) acc1[c][j] = bb;
    }
    #pragma unroll 2
    for (int kk = 0; kk < D; ++kk) {
        float4 xa = *(const float4*)(xs + kk * NB);
        float4 xb = *(const float4*)(xs + kk * NB + 4);
        float xv[NB] = {xa.x, xa.y, xa.z, xa.w, xb.x, xb.y, xb.z, xb.w};
        float w0 = W1[kk * HID + t];
        float w1 = W1[kk * HID + t + 128];
        float w2 = W1[kk * HID + t + 256];
        float w3 = W1[kk * HID + t + 384];
        #pragma unroll
        for (int j = 0; j < NB; ++j) {
            acc1[0][j] = fmaf(xv[j], w0, acc1[0][j]);
            acc1[1][j] = fmaf(xv[j], w1, acc1[1][j]);
            acc1[2][j] = fmaf(xv[j], w2, acc1[2][j]);
            acc1[3][j] = fmaf(xv[j], w3, acc1[3][j]);
        }
    }
    #pragma unroll
    for (int c = 0; c < 4; ++c)
        #pragma unroll
        for (int j = 0; j < NB; ++j)
            hid[j * HID + t + 128 * c] = gelu_tanh(acc1[c][j]);
    __syncthreads();

    float acc2[NB];
    float b2v = b2[t];
    #pragma unroll
    for (int j = 0; j < NB; ++j) acc2[j] = b2v;
    for (int kk = 0; kk < HID; kk += 4) {
        float w0 = W2[(kk + 0) * D + t];
        float w1 = W2[(kk + 1) * D + t];
        float w2 = W2[(kk + 2) * D + t];
        float w3 = W2[(kk + 3) * D + t];
        #pragma unroll
        for (int j = 0; j < NB; ++j) {
            float4 hv = *(const float4*)(hid + j * HID + kk);
            acc2[j] += hv.x * w0 + hv.y * w1 + hv.z * w2 + hv.w * w3;
        }
    }
    #pragma unroll
    for (int j = 0; j < NB; ++j) {
        int n = n0 + j;
        if (n < N) out[(size_t)n * D + t] = xs[t * NB + j] + acc2[j];
    }
}

// ---------- launch ----------
extern "C" void kernel_launch(void* const* d_in, const int* in_sizes, int n_in,
                              void* d_out, int out_size, void* d_ws, size_t ws_size,
                              hipStream_t stream) {
    const float* x   = (const float*)d_in[0];
    const int*   ei  = (const int*)d_in[1];
    const float* Wq  = (const float*)d_in[2];
    const float* bq  = (const float*)d_in[3];
    const float* Wk  = (const float*)d_in[4];
    const float* bk  = (const float*)d_in[5];
    const float* Wv  = (const float*)d_in[6];
    const float* bv  = (const float*)d_in[7];
    const float* Wo  = (const float*)d_in[8];
    const float* bo  = (const float*)d_in[9];
    const float* lng = (const float*)d_in[10];
    const float* lnb = (const float*)d_in[11];
    const float* W1  = (const float*)d_in[12];
    const float* b1  = (const float*)d_in[13];
    const float* W2  = (const float*)d_in[14];
    const float* b2  = (const float*)d_in[15];
    float* out = (float*)d_out;

    int N = in_sizes[0] / D;
    int E = in_sizes[1] / 2;
    const int* srcp = ei;
    const int* dstp = ei + E;

    // workspace layout
    float* q     = (float*)d_ws;
    float* k     = q + (size_t)N * D;
    float* v     = k + (size_t)N * D;
    float* agg   = v + (size_t)N * D;
    float* lnout = agg + (size_t)N * D;
    int*   deg     = (int*)(lnout + (size_t)N * D);
    int*   row_ptr = deg + N;            // N+1
    int*   cursor  = row_ptr + N + 1;
    int*   col     = cursor + N;         // E

    int nblk = (N + NB - 1) / NB;
    int eblk = (E + 255) / 256;

    k0_zero_deg<<<(N + 255) / 256, 256, 0, stream>>>(deg, N);
    k1_qkv<<<nblk, D, 0, stream>>>(x, Wq, bq, Wk, bk, Wv, bv, q, k, v, N);
    k_hist<<<eblk, 256, 0, stream>>>(dstp, deg, E);
    k_scan<<<1, 1024, 0, stream>>>(deg, row_ptr, cursor, N);
    k_scatter<<<eblk, 256, 0, stream>>>(srcp, dstp, cursor, col, E);
    k_attn<<<(N + WPB - 1) / WPB, WPB * 64, 0, stream>>>(q, k, v, row_ptr, col, agg, N);
    k5_wo_ln<<<nblk, D, 0, stream>>>(agg, Wo, bo, x, lng, lnb, lnout, N);
    k6_mlp<<<nblk, D, 0, stream>>>(lnout, W1, b1, W2, b2, out, N);
}

// Round 3
// 498.945 us; speedup vs baseline: 1.6927x; 1.4005x over previous
//
#include <hip/hip_runtime.h>
#include <math.h>

#define D   128
#define HH  4
#define HD  32
#define NB  8
#define HID 512
#define WPB 4     // nodes (waves) per block in fused attention
#define MT  32    // node tile for MFMA MLP
#define XP  136   // 128+8 padded LDS row (bf16 elems)
#define HP  520   // 512+8 padded hidden row (bf16 elems)

typedef __attribute__((ext_vector_type(8))) short bf16x8;  // 8 bf16 (4 VGPRs)
typedef __attribute__((ext_vector_type(4))) float f32x4;   // MFMA C/D frag

// fp32 -> bf16 bits, round-to-nearest-even
__device__ __forceinline__ short f2b(float f) {
    unsigned u = __float_as_uint(f);
    unsigned r = (u + 0x7FFFu + ((u >> 16) & 1u)) >> 16;
    return (short)r;
}

__device__ __forceinline__ float gelu_tanh(float x) {
    float x3 = x * x * x;
    float u = 0.7978845608028654f * (x + 0.044715f * x3);
    return 0.5f * x * (1.0f + tanhf(u));
}

// ---------- K0: zero degree array ----------
__global__ void k0_zero_deg(int* __restrict__ deg, int N) {
    int i = blockIdx.x * blockDim.x + threadIdx.x;
    if (i < N) deg[i] = 0;
}

// ---------- prep: W1,W2 -> bf16 transposed [n][k] ----------
__global__ void k_prep(const float* __restrict__ W1, const float* __restrict__ W2,
                       short* __restrict__ Wt1, short* __restrict__ Wt2) {
    int i = blockIdx.x * 256 + threadIdx.x;     // 65536 threads total
    {   // Wt1[n][k] = bf16(W1[k][n]), n<512, k<128
        int n = i >> 7, k = i & 127;
        Wt1[i] = f2b(W1[k * HID + n]);
    }
    {   // Wt2[n][k] = bf16(W2[k][n]), n<128, k<512
        int n = i >> 9, k = i & 511;
        Wt2[i] = f2b(W2[k * D + n]);
    }
}

// ---------- K1: q,k,v = x@W + b  (fp32 vector path, unchanged) ----------
__global__ void k1_qkv(const float* __restrict__ x,
                       const float* __restrict__ Wq, const float* __restrict__ bq,
                       const float* __restrict__ Wk, const float* __restrict__ bk,
                       const float* __restrict__ Wv, const float* __restrict__ bv,
                       float* __restrict__ q, float* __restrict__ k, float* __restrict__ v,
                       int N) {
    __shared__ float xs[D * NB];
    int n0 = blockIdx.x * NB;
    int t  = threadIdx.x;
    #pragma unroll
    for (int j = 0; j < NB; ++j) {
        int n = n0 + j;
        xs[t * NB + j] = (n < N) ? x[(size_t)n * D + t] : 0.0f;
    }
    __syncthreads();

    float aq[NB], ak[NB], av[NB];
    float bqv = bq[t], bkv = bk[t], bvv = bv[t];
    #pragma unroll
    for (int j = 0; j < NB; ++j) { aq[j] = bqv; ak[j] = bkv; av[j] = bvv; }

    #pragma unroll 4
    for (int kk = 0; kk < D; ++kk) {
        float wq = Wq[kk * D + t], wk = Wk[kk * D + t], wv = Wv[kk * D + t];
        float4 xa = *(const float4*)(xs + kk * NB);
        float4 xb = *(const float4*)(xs + kk * NB + 4);
        float xv[NB] = {xa.x, xa.y, xa.z, xa.w, xb.x, xb.y, xb.z, xb.w};
        #pragma unroll
        for (int j = 0; j < NB; ++j) {
            aq[j] = fmaf(xv[j], wq, aq[j]);
            ak[j] = fmaf(xv[j], wk, ak[j]);
            av[j] = fmaf(xv[j], wv, av[j]);
        }
    }
    #pragma unroll
    for (int j = 0; j < NB; ++j) {
        int n = n0 + j;
        if (n < N) {
            q[(size_t)n * D + t] = aq[j];
            k[(size_t)n * D + t] = ak[j];
            v[(size_t)n * D + t] = av[j];
        }
    }
}

// ---------- CSR build ----------
__global__ void k_hist(const int* __restrict__ dst, int* __restrict__ deg, int E) {
    int i = blockIdx.x * blockDim.x + threadIdx.x;
    if (i < E) atomicAdd(&deg[dst[i]], 1);
}

__global__ void k_scan(const int* __restrict__ deg, int* __restrict__ row_ptr,
                       int* __restrict__ cursor, int N) {
    __shared__ int sums[1024];
    int t = threadIdx.x;
    int CH = (N + 1023) / 1024;
    int lo = t * CH, hi = min(lo + CH, N);
    int s = 0;
    for (int i = lo; i < hi; ++i) s += deg[i];
    sums[t] = s;
    __syncthreads();
    for (int off = 1; off < 1024; off <<= 1) {
        int vv = (t >= off) ? sums[t - off] : 0;
        __syncthreads();
        sums[t] += vv;
        __syncthreads();
    }
    int base = (t == 0) ? 0 : sums[t - 1];
    for (int i = lo; i < hi; ++i) {
        row_ptr[i] = base;
        cursor[i]  = base;
        base += deg[i];
    }
    if (t == 0) row_ptr[N] = sums[1023];
}

__global__ void k_scatter(const int* __restrict__ src, const int* __restrict__ dst,
                          int* __restrict__ cursor, int* __restrict__ col, int E) {
    int i = blockIdx.x * blockDim.x + threadIdx.x;
    if (i < E) {
        int d = dst[i];
        int pos = atomicAdd(&cursor[d], 1);
        col[pos] = src[i];
    }
}

// ---------- fused attention (unchanged) ----------
__global__ void k_attn(const float* __restrict__ q, const float* __restrict__ k,
                       const float* __restrict__ v, const int* __restrict__ row_ptr,
                       const int* __restrict__ col, float* __restrict__ agg, int N) {
    int wave = threadIdx.x >> 6;
    int lane = threadIdx.x & 63;
    int n = blockIdx.x * WPB + wave;
    if (n >= N) return;
    int beg = row_ptr[n], end = row_ptr[n + 1];

    float2 qv = *(const float2*)(q + (size_t)n * D + 2 * lane);

    float m = -INFINITY, l = 0.f;
    float2 acc = {0.f, 0.f};

    float2 kv, vv;
    if (beg < end) {
        int s0 = col[beg];
        kv = *(const float2*)(k + (size_t)s0 * D + 2 * lane);
        vv = *(const float2*)(v + (size_t)s0 * D + 2 * lane);
    }
    for (int p = beg; p < end; ++p) {
        float2 ck = kv, cv = vv;
        if (p + 1 < end) {
            int s1 = col[p + 1];
            kv = *(const float2*)(k + (size_t)s1 * D + 2 * lane);
            vv = *(const float2*)(v + (size_t)s1 * D + 2 * lane);
        }
        float part = qv.x * ck.x + qv.y * ck.y;
        part += __shfl_xor(part, 1);
        part += __shfl_xor(part, 2);
        part += __shfl_xor(part, 4);
        part += __shfl_xor(part, 8);
        float sc = part * 0.17677669529663687f;
        float mn = fmaxf(m, sc);
        float alpha = __expf(m - mn);
        float pe    = __expf(sc - mn);
        l = l * alpha + pe;
        acc.x = acc.x * alpha + pe * cv.x;
        acc.y = acc.y * alpha + pe * cv.y;
        m = mn;
    }
    float inv = (l > 0.f) ? 1.f / l : 0.f;
    float2 o = {acc.x * inv, acc.y * inv};
    *(float2*)(agg + (size_t)n * D + 2 * lane) = o;
}

// ---------- K5: out = LN(agg @ Wo + bo + residual) (unchanged) ----------
__global__ void k5_wo_ln(const float* __restrict__ agg,
                         const float* __restrict__ Wo, const float* __restrict__ bo,
                         const float* __restrict__ x, const float* __restrict__ g,
                         const float* __restrict__ b, float* __restrict__ lnout, int N) {
    __shared__ float xs[D * NB];
    __shared__ float ps[NB * 16], ps2[NB * 16];
    __shared__ float mu[NB], rstd[NB];
    int n0 = blockIdx.x * NB;
    int t  = threadIdx.x;
    #pragma unroll
    for (int j = 0; j < NB; ++j) {
        int n = n0 + j;
        xs[t * NB + j] = (n < N) ? agg[(size_t)n * D + t] : 0.0f;
    }
    __syncthreads();

    float acc[NB];
    float bov = bo[t];
    #pragma unroll
    for (int j = 0; j < NB; ++j) acc[j] = bov;

    #pragma unroll 4
    for (int kk = 0; kk < D; ++kk) {
        float w = Wo[kk * D + t];
        float4 xa = *(const float4*)(xs + kk * NB);
        float4 xb = *(const float4*)(xs + kk * NB + 4);
        float xv[NB] = {xa.x, xa.y, xa.z, xa.w, xb.x, xb.y, xb.z, xb.w};
        #pragma unroll
        for (int j = 0; j < NB; ++j) acc[j] = fmaf(xv[j], w, acc[j]);
    }
    #pragma unroll
    for (int j = 0; j < NB; ++j) {
        int n = n0 + j;
        if (n < N) acc[j] += x[(size_t)n * D + t];
    }
    __syncthreads();
    #pragma unroll
    for (int j = 0; j < NB; ++j) xs[j * D + t] = acc[j];
    __syncthreads();

    int nn = t >> 4, lane = t & 15;
    float s1 = 0.f, s2 = 0.f;
    #pragma unroll
    for (int c = lane; c < D; c += 16) {
        float vvv = xs[nn * D + c];
        s1 += vvv; s2 += vvv * vvv;
    }
    ps[t] = s1; ps2[t] = s2;
    __syncthreads();
    if (t < NB) {
        float mm = 0.f, m2 = 0.f;
        #pragma unroll
        for (int i = 0; i < 16; ++i) { mm += ps[t * 16 + i]; m2 += ps2[t * 16 + i]; }
        mm *= (1.0f / D); m2 *= (1.0f / D);
        float var = m2 - mm * mm;
        mu[t] = mm; rstd[t] = rsqrtf(var + 1e-5f);
    }
    __syncthreads();
    float gv = g[t], bv = b[t];
    #pragma unroll
    for (int j = 0; j < NB; ++j) {
        int n = n0 + j;
        if (n < N) lnout[(size_t)n * D + t] = (acc[j] - mu[j]) * rstd[j] * gv + bv;
    }
}

// ---------- K6 (MFMA): out = ln + gelu(ln@W1+b1)@W2+b2 ----------
// 32 nodes/block, 4 waves. Weights pre-transposed bf16 [n][k] (B-frag friendly).
// A-frag: A[m=lane&15][k=quad*8+j]; C/D: col=lane&15, row=quad*4+reg (verified layouts).
__global__ __launch_bounds__(256) void k6_mlp_mfma(
        const float* __restrict__ ln, const short* __restrict__ Wt1,
        const float* __restrict__ b1, const short* __restrict__ Wt2,
        const float* __restrict__ b2, float* __restrict__ out, int N) {
    __shared__ short xs[MT * XP];    // X tile  [m][k], bf16, padded
    __shared__ short hid[MT * HP];   // hidden  [m][k], bf16, padded
    int m0 = blockIdx.x * MT;
    int t = threadIdx.x;
    int wave = t >> 6, lane = t & 63, quad = lane >> 4, l16 = lane & 15;

    // stage X tile: fp32 -> bf16, 256 threads x 16 elems
    {
        int row = t >> 3, c0 = (t & 7) * 16;
        int n = m0 + row;
        #pragma unroll
        for (int c = 0; c < 16; c += 4) {
            float4 xv = {0.f, 0.f, 0.f, 0.f};
            if (n < N) xv = *(const float4*)(ln + (size_t)n * D + c0 + c);
            xs[row * XP + c0 + c + 0] = f2b(xv.x);
            xs[row * XP + c0 + c + 1] = f2b(xv.y);
            xs[row * XP + c0 + c + 2] = f2b(xv.z);
            xs[row * XP + c0 + c + 3] = f2b(xv.w);
        }
    }
    __syncthreads();

    // phase 1: hidden = gelu(X @ W1 + b1); wave owns hidden cols [wave*128, +128)
    f32x4 acc1[2][8];
    #pragma unroll
    for (int nt = 0; nt < 8; ++nt) {
        float bb = b1[wave * 128 + nt * 16 + l16];
        acc1[0][nt] = (f32x4){bb, bb, bb, bb};
        acc1[1][nt] = (f32x4){bb, bb, bb, bb};
    }
    #pragma unroll
    for (int kt = 0; kt < 4; ++kt) {
        int klane = kt * 32 + quad * 8;
        bf16x8 a0 = *(const bf16x8*)(xs + (l16)      * XP + klane);
        bf16x8 a1 = *(const bf16x8*)(xs + (16 + l16) * XP + klane);
        #pragma unroll
        for (int nt = 0; nt < 8; ++nt) {
            bf16x8 bf = *(const bf16x8*)(Wt1 + (size_t)(wave * 128 + nt * 16 + l16) * D + klane);
            acc1[0][nt] = __builtin_amdgcn_mfma_f32_16x16x32_bf16(a0, bf, acc1[0][nt], 0, 0, 0);
            acc1[1][nt] = __builtin_amdgcn_mfma_f32_16x16x32_bf16(a1, bf, acc1[1][nt], 0, 0, 0);
        }
    }
    #pragma unroll
    for (int mt = 0; mt < 2; ++mt)
        #pragma unroll
        for (int nt = 0; nt < 8; ++nt)
            #pragma unroll
            for (int r = 0; r < 4; ++r) {
                int row = mt * 16 + quad * 4 + r;
                int colh = wave * 128 + nt * 16 + l16;
                hid[row * HP + colh] = f2b(gelu_tanh(acc1[mt][nt][r]));
            }
    __syncthreads();

    // phase 2: out = ln + hid @ W2 + b2; wave owns out cols [wave*32, +32)
    f32x4 acc2[2][2];
    #pragma unroll
    for (int nt = 0; nt < 2; ++nt) {
        float bb = b2[wave * 32 + nt * 16 + l16];
        acc2[0][nt] = (f32x4){bb, bb, bb, bb};
        acc2[1][nt] = (f32x4){bb, bb, bb, bb};
    }
    #pragma unroll 4
    for (int kt = 0; kt < 16; ++kt) {
        int klane = kt * 32 + quad * 8;
        bf16x8 a0 = *(const bf16x8*)(hid + (l16)      * HP + klane);
        bf16x8 a1 = *(const bf16x8*)(hid + (16 + l16) * HP + klane);
        #pragma unroll
        for (int nt = 0; nt < 2; ++nt) {
            bf16x8 bf = *(const bf16x8*)(Wt2 + (size_t)(wave * 32 + nt * 16 + l16) * HID + klane);
            acc2[0][nt] = __builtin_amdgcn_mfma_f32_16x16x32_bf16(a0, bf, acc2[0][nt], 0, 0, 0);
            acc2[1][nt] = __builtin_amdgcn_mfma_f32_16x16x32_bf16(a1, bf, acc2[1][nt], 0, 0, 0);
        }
    }
    #pragma unroll
    for (int mt = 0; mt < 2; ++mt)
        #pragma unroll
        for (int nt = 0; nt < 2; ++nt)
            #pragma unroll
            for (int r = 0; r < 4; ++r) {
                int n = m0 + mt * 16 + quad * 4 + r;
                int c = wave * 32 + nt * 16 + l16;
                if (n < N)
                    out[(size_t)n * D + c] = ln[(size_t)n * D + c] + acc2[mt][nt][r];
            }
}

// ---------- launch ----------
extern "C" void kernel_launch(void* const* d_in, const int* in_sizes, int n_in,
                              void* d_out, int out_size, void* d_ws, size_t ws_size,
                              hipStream_t stream) {
    const float* x   = (const float*)d_in[0];
    const int*   ei  = (const int*)d_in[1];
    const float* Wq  = (const float*)d_in[2];
    const float* bq  = (const float*)d_in[3];
    const float* Wk  = (const float*)d_in[4];
    const float* bk  = (const float*)d_in[5];
    const float* Wv  = (const float*)d_in[6];
    const float* bv  = (const float*)d_in[7];
    const float* Wo  = (const float*)d_in[8];
    const float* bo  = (const float*)d_in[9];
    const float* lng = (const float*)d_in[10];
    const float* lnb = (const float*)d_in[11];
    const float* W1  = (const float*)d_in[12];
    const float* b1  = (const float*)d_in[13];
    const float* W2  = (const float*)d_in[14];
    const float* b2  = (const float*)d_in[15];
    float* out = (float*)d_out;

    int N = in_sizes[0] / D;
    int E = in_sizes[1] / 2;
    const int* srcp = ei;
    const int* dstp = ei + E;

    // workspace layout (Wt first for 16B alignment of bf16x8 loads)
    short* Wt1  = (short*)d_ws;                    // 512*128
    short* Wt2  = Wt1 + 512 * 128;                 // 128*512
    float* q    = (float*)(Wt2 + 512 * 128);
    float* k    = q + (size_t)N * D;
    float* v    = k + (size_t)N * D;
    float* agg  = v + (size_t)N * D;
    float* lnout = agg + (size_t)N * D;
    int*   deg     = (int*)(lnout + (size_t)N * D);
    int*   row_ptr = deg + N;                      // N+1
    int*   cursor  = row_ptr + N + 1;
    int*   col     = cursor + N;                   // E

    int nblk  = (N + NB - 1) / NB;
    int nblk2 = (N + MT - 1) / MT;
    int eblk  = (E + 255) / 256;

    k0_zero_deg<<<(N + 255) / 256, 256, 0, stream>>>(deg, N);
    k_prep<<<(512 * 128) / 256, 256, 0, stream>>>(W1, W2, Wt1, Wt2);
    k1_qkv<<<nblk, D, 0, stream>>>(x, Wq, bq, Wk, bk, Wv, bv, q, k, v, N);
    k_hist<<<eblk, 256, 0, stream>>>(dstp, deg, E);
    k_scan<<<1, 1024, 0, stream>>>(deg, row_ptr, cursor, N);
    k_scatter<<<eblk, 256, 0, stream>>>(srcp, dstp, cursor, col, E);
    k_attn<<<(N + WPB - 1) / WPB, WPB * 64, 0, stream>>>(q, k, v, row_ptr, col, agg, N);
    k5_wo_ln<<<nblk, D, 0, stream>>>(agg, Wo, bo, x, lng, lnb, lnout, N);
    k6_mlp_mfma<<<nblk2, 256, 0, stream>>>(lnout, Wt1, b1, Wt2, b2, out, N);
}

// Round 4
// 441.623 us; speedup vs baseline: 1.9124x; 1.1298x over previous
//
#include <hip/hip_runtime.h>
#include <math.h>

#define D   128
#define HH  4
#define HD  32
#define NB  8
#define HID 512
#define WPB 4     // nodes (waves) per block in fused attention
#define MT  32    // node tile for MFMA kernels
#define XP  136   // 128+8 padded LDS row (bf16 elems)
#define HP  520   // 512+8 padded hidden row (bf16 elems)
#define KVP 264   // 256+8 padded kv LDS row (bf16 elems)

typedef __attribute__((ext_vector_type(8))) short bf16x8;  // 8 bf16 (4 VGPRs)
typedef __attribute__((ext_vector_type(4))) float f32x4;   // MFMA C/D frag

// fp32 -> bf16 bits, round-to-nearest-even
__device__ __forceinline__ short f2b(float f) {
    unsigned u = __float_as_uint(f);
    unsigned r = (u + 0x7FFFu + ((u >> 16) & 1u)) >> 16;
    return (short)r;
}
__device__ __forceinline__ float b2f(short s) {
    return __uint_as_float(((unsigned)(unsigned short)s) << 16);
}

__device__ __forceinline__ float gelu_tanh(float x) {
    float x3 = x * x * x;
    float u = 0.7978845608028654f * (x + 0.044715f * x3);
    return 0.5f * x * (1.0f + tanhf(u));
}

// ---------- K0: zero degree array ----------
__global__ void k0_zero_deg(int* __restrict__ deg, int N) {
    int i = blockIdx.x * blockDim.x + threadIdx.x;
    if (i < N) deg[i] = 0;
}

// ---------- prep: all weights -> bf16 transposed [n][k] ----------
__global__ void k_prep(const float* __restrict__ W1, const float* __restrict__ W2,
                       const float* __restrict__ Wq, const float* __restrict__ Wk,
                       const float* __restrict__ Wv,
                       short* __restrict__ Wt1, short* __restrict__ Wt2,
                       short* __restrict__ Wtq, short* __restrict__ Wtk,
                       short* __restrict__ Wtv) {
    int i = blockIdx.x * 256 + threadIdx.x;     // 65536 threads
    {   int n = i >> 7, k = i & 127; Wt1[i] = f2b(W1[k * HID + n]); }
    {   int n = i >> 9, k = i & 511; Wt2[i] = f2b(W2[k * D + n]); }
    if (i < D * D) {
        int n = i >> 7, k = i & 127;
        Wtq[i] = f2b(Wq[k * D + n]);
        Wtk[i] = f2b(Wk[k * D + n]);
        Wtv[i] = f2b(Wv[k * D + n]);
    }
}

// ---------- K1 (MFMA): q fp32, kv bf16 interleaved ----------
// 32 nodes/block, 4 waves; wave w owns output cols [w*32, w*32+32) of q,k,v.
// kv layout: kv[node*256 + p*4 + {0,1}] = k[2p],k[2p+1]; +{2,3} = v[2p],v[2p+1]
__global__ __launch_bounds__(256) void k1_qkv_mfma(
        const float* __restrict__ x,
        const short* __restrict__ Wtq, const float* __restrict__ bq,
        const short* __restrict__ Wtk, const float* __restrict__ bk,
        const short* __restrict__ Wtv, const float* __restrict__ bv,
        float* __restrict__ q, short* __restrict__ kv, int N) {
    __shared__ short xs[MT * XP];
    __shared__ short kvs[MT * KVP];
    int m0 = blockIdx.x * MT;
    int t = threadIdx.x;
    int wave = t >> 6, lane = t & 63, quad = lane >> 4, l16 = lane & 15;

    // stage X tile fp32 -> bf16
    {
        int row = t >> 3, c0 = (t & 7) * 16;
        int n = m0 + row;
        #pragma unroll
        for (int c = 0; c < 16; c += 4) {
            float4 xv = {0.f, 0.f, 0.f, 0.f};
            if (n < N) xv = *(const float4*)(x + (size_t)n * D + c0 + c);
            xs[row * XP + c0 + c + 0] = f2b(xv.x);
            xs[row * XP + c0 + c + 1] = f2b(xv.y);
            xs[row * XP + c0 + c + 2] = f2b(xv.z);
            xs[row * XP + c0 + c + 3] = f2b(xv.w);
        }
    }
    __syncthreads();

    f32x4 accq[2][2], acck[2][2], accv[2][2];
    #pragma unroll
    for (int nt = 0; nt < 2; ++nt) {
        int c = wave * 32 + nt * 16 + l16;
        float q0 = bq[c], k0 = bk[c], v0 = bv[c];
        #pragma unroll
        for (int mt = 0; mt < 2; ++mt) {
            accq[mt][nt] = (f32x4){q0, q0, q0, q0};
            acck[mt][nt] = (f32x4){k0, k0, k0, k0};
            accv[mt][nt] = (f32x4){v0, v0, v0, v0};
        }
    }
    #pragma unroll
    for (int kt = 0; kt < 4; ++kt) {
        int klane = kt * 32 + quad * 8;
        bf16x8 a0 = *(const bf16x8*)(xs + (l16)      * XP + klane);
        bf16x8 a1 = *(const bf16x8*)(xs + (16 + l16) * XP + klane);
        #pragma unroll
        for (int nt = 0; nt < 2; ++nt) {
            int c = wave * 32 + nt * 16 + l16;
            bf16x8 fq = *(const bf16x8*)(Wtq + (size_t)c * D + klane);
            bf16x8 fk = *(const bf16x8*)(Wtk + (size_t)c * D + klane);
            bf16x8 fv = *(const bf16x8*)(Wtv + (size_t)c * D + klane);
            accq[0][nt] = __builtin_amdgcn_mfma_f32_16x16x32_bf16(a0, fq, accq[0][nt], 0, 0, 0);
            accq[1][nt] = __builtin_amdgcn_mfma_f32_16x16x32_bf16(a1, fq, accq[1][nt], 0, 0, 0);
            acck[0][nt] = __builtin_amdgcn_mfma_f32_16x16x32_bf16(a0, fk, acck[0][nt], 0, 0, 0);
            acck[1][nt] = __builtin_amdgcn_mfma_f32_16x16x32_bf16(a1, fk, acck[1][nt], 0, 0, 0);
            accv[0][nt] = __builtin_amdgcn_mfma_f32_16x16x32_bf16(a0, fv, accv[0][nt], 0, 0, 0);
            accv[1][nt] = __builtin_amdgcn_mfma_f32_16x16x32_bf16(a1, fv, accv[1][nt], 0, 0, 0);
        }
    }
    // q: direct fp32 store; k,v -> LDS interleaved bf16
    #pragma unroll
    for (int mt = 0; mt < 2; ++mt)
        #pragma unroll
        for (int nt = 0; nt < 2; ++nt)
            #pragma unroll
            for (int r = 0; r < 4; ++r) {
                int row = mt * 16 + quad * 4 + r;
                int n = m0 + row;
                int c = wave * 32 + nt * 16 + l16;
                if (n < N) q[(size_t)n * D + c] = accq[mt][nt][r];
                int base = row * KVP + (c >> 1) * 4 + (c & 1);
                kvs[base]     = f2b(acck[mt][nt][r]);
                kvs[base + 2] = f2b(accv[mt][nt][r]);
            }
    __syncthreads();
    // coop write-out: 8 threads per row, 32 shorts each
    {
        int row = t >> 3, c0 = (t & 7) * 32;
        int n = m0 + row;
        if (n < N) {
            #pragma unroll
            for (int i = 0; i < 4; ++i)
                *(uint4*)(kv + (size_t)n * 256 + c0 + i * 8) =
                    *(const uint4*)(kvs + row * KVP + c0 + i * 8);
        }
    }
}

// ---------- CSR build ----------
__global__ void k_hist(const int* __restrict__ dst, int* __restrict__ deg, int E) {
    int i = blockIdx.x * blockDim.x + threadIdx.x;
    if (i < E) atomicAdd(&deg[dst[i]], 1);
}

__global__ void k_scan(const int* __restrict__ deg, int* __restrict__ row_ptr,
                       int* __restrict__ cursor, int N) {
    __shared__ int sums[1024];
    int t = threadIdx.x;
    int CH = (N + 1023) / 1024;
    int lo = t * CH, hi = min(lo + CH, N);
    int s = 0;
    for (int i = lo; i < hi; ++i) s += deg[i];
    sums[t] = s;
    __syncthreads();
    for (int off = 1; off < 1024; off <<= 1) {
        int vv = (t >= off) ? sums[t - off] : 0;
        __syncthreads();
        sums[t] += vv;
        __syncthreads();
    }
    int base = (t == 0) ? 0 : sums[t - 1];
    for (int i = lo; i < hi; ++i) {
        row_ptr[i] = base;
        cursor[i]  = base;
        base += deg[i];
    }
    if (t == 0) row_ptr[N] = sums[1023];
}

__global__ void k_scatter(const int* __restrict__ src, const int* __restrict__ dst,
                          int* __restrict__ cursor, int* __restrict__ col, int E) {
    int i = blockIdx.x * blockDim.x + threadIdx.x;
    if (i < E) {
        int d = dst[i];
        int pos = atomicAdd(&cursor[d], 1);
        col[pos] = src[i];
    }
}

// ---------- fused attention: bf16 interleaved kv gather ----------
__global__ void k_attn(const float* __restrict__ q, const short* __restrict__ kv,
                       const int* __restrict__ row_ptr, const int* __restrict__ col,
                       float* __restrict__ agg, int N) {
    int wave = threadIdx.x >> 6;
    int lane = threadIdx.x & 63;
    int n = blockIdx.x * WPB + wave;
    if (n >= N) return;
    int beg = row_ptr[n], end = row_ptr[n + 1];

    float2 qv = *(const float2*)(q + (size_t)n * D + 2 * lane);

    float m = -INFINITY, l = 0.f;
    float2 acc = {0.f, 0.f};

    short4 cur;
    if (beg < end) {
        int s0 = col[beg];
        cur = *(const short4*)(kv + (size_t)s0 * 256 + 4 * lane);
    }
    for (int p = beg; p < end; ++p) {
        short4 ckv = cur;
        if (p + 1 < end) {
            int s1 = col[p + 1];
            cur = *(const short4*)(kv + (size_t)s1 * 256 + 4 * lane);
        }
        float kx = b2f(ckv.x), ky = b2f(ckv.y);
        float vx = b2f(ckv.z), vy = b2f(ckv.w);
        float part = qv.x * kx + qv.y * ky;
        part += __shfl_xor(part, 1);
        part += __shfl_xor(part, 2);
        part += __shfl_xor(part, 4);
        part += __shfl_xor(part, 8);
        float sc = part * 0.17677669529663687f;
        float mn = fmaxf(m, sc);
        float alpha = __expf(m - mn);
        float pe    = __expf(sc - mn);
        l = l * alpha + pe;
        acc.x = acc.x * alpha + pe * vx;
        acc.y = acc.y * alpha + pe * vy;
        m = mn;
    }
    float inv = (l > 0.f) ? 1.f / l : 0.f;
    float2 o = {acc.x * inv, acc.y * inv};
    *(float2*)(agg + (size_t)n * D + 2 * lane) = o;
}

// ---------- K5: out = LN(agg @ Wo + bo + residual) ----------
__global__ void k5_wo_ln(const float* __restrict__ agg,
                         const float* __restrict__ Wo, const float* __restrict__ bo,
                         const float* __restrict__ x, const float* __restrict__ g,
                         const float* __restrict__ b, float* __restrict__ lnout, int N) {
    __shared__ float xs[D * NB];
    __shared__ float ps[NB * 16], ps2[NB * 16];
    __shared__ float mu[NB], rstd[NB];
    int n0 = blockIdx.x * NB;
    int t  = threadIdx.x;
    #pragma unroll
    for (int j = 0; j < NB; ++j) {
        int n = n0 + j;
        xs[t * NB + j] = (n < N) ? agg[(size_t)n * D + t] : 0.0f;
    }
    __syncthreads();

    float acc[NB];
    float bov = bo[t];
    #pragma unroll
    for (int j = 0; j < NB; ++j) acc[j] = bov;

    #pragma unroll 4
    for (int kk = 0; kk < D; ++kk) {
        float w = Wo[kk * D + t];
        float4 xa = *(const float4*)(xs + kk * NB);
        float4 xb = *(const float4*)(xs + kk * NB + 4);
        float xv[NB] = {xa.x, xa.y, xa.z, xa.w, xb.x, xb.y, xb.z, xb.w};
        #pragma unroll
        for (int j = 0; j < NB; ++j) acc[j] = fmaf(xv[j], w, acc[j]);
    }
    #pragma unroll
    for (int j = 0; j < NB; ++j) {
        int n = n0 + j;
        if (n < N) acc[j] += x[(size_t)n * D + t];
    }
    __syncthreads();
    #pragma unroll
    for (int j = 0; j < NB; ++j) xs[j * D + t] = acc[j];
    __syncthreads();

    int nn = t >> 4, lane = t & 15;
    float s1 = 0.f, s2 = 0.f;
    #pragma unroll
    for (int c = lane; c < D; c += 16) {
        float vvv = xs[nn * D + c];
        s1 += vvv; s2 += vvv * vvv;
    }
    ps[t] = s1; ps2[t] = s2;
    __syncthreads();
    if (t < NB) {
        float mm = 0.f, m2 = 0.f;
        #pragma unroll
        for (int i = 0; i < 16; ++i) { mm += ps[t * 16 + i]; m2 += ps2[t * 16 + i]; }
        mm *= (1.0f / D); m2 *= (1.0f / D);
        float var = m2 - mm * mm;
        mu[t] = mm; rstd[t] = rsqrtf(var + 1e-5f);
    }
    __syncthreads();
    float gv = g[t], bv = b[t];
    #pragma unroll
    for (int j = 0; j < NB; ++j) {
        int n = n0 + j;
        if (n < N) lnout[(size_t)n * D + t] = (acc[j] - mu[j]) * rstd[j] * gv + bv;
    }
}

// ---------- K6 (MFMA): out = ln + gelu(ln@W1+b1)@W2+b2 ----------
__global__ __launch_bounds__(256) void k6_mlp_mfma(
        const float* __restrict__ ln, const short* __restrict__ Wt1,
        const float* __restrict__ b1, const short* __restrict__ Wt2,
        const float* __restrict__ b2, float* __restrict__ out, int N) {
    __shared__ short xs[MT * XP];
    __shared__ short hid[MT * HP];
    int m0 = blockIdx.x * MT;
    int t = threadIdx.x;
    int wave = t >> 6, lane = t & 63, quad = lane >> 4, l16 = lane & 15;

    {
        int row = t >> 3, c0 = (t & 7) * 16;
        int n = m0 + row;
        #pragma unroll
        for (int c = 0; c < 16; c += 4) {
            float4 xv = {0.f, 0.f, 0.f, 0.f};
            if (n < N) xv = *(const float4*)(ln + (size_t)n * D + c0 + c);
            xs[row * XP + c0 + c + 0] = f2b(xv.x);
            xs[row * XP + c0 + c + 1] = f2b(xv.y);
            xs[row * XP + c0 + c + 2] = f2b(xv.z);
            xs[row * XP + c0 + c + 3] = f2b(xv.w);
        }
    }
    __syncthreads();

    f32x4 acc1[2][8];
    #pragma unroll
    for (int nt = 0; nt < 8; ++nt) {
        float bb = b1[wave * 128 + nt * 16 + l16];
        acc1[0][nt] = (f32x4){bb, bb, bb, bb};
        acc1[1][nt] = (f32x4){bb, bb, bb, bb};
    }
    #pragma unroll
    for (int kt = 0; kt < 4; ++kt) {
        int klane = kt * 32 + quad * 8;
        bf16x8 a0 = *(const bf16x8*)(xs + (l16)      * XP + klane);
        bf16x8 a1 = *(const bf16x8*)(xs + (16 + l16) * XP + klane);
        #pragma unroll
        for (int nt = 0; nt < 8; ++nt) {
            bf16x8 bf = *(const bf16x8*)(Wt1 + (size_t)(wave * 128 + nt * 16 + l16) * D + klane);
            acc1[0][nt] = __builtin_amdgcn_mfma_f32_16x16x32_bf16(a0, bf, acc1[0][nt], 0, 0, 0);
            acc1[1][nt] = __builtin_amdgcn_mfma_f32_16x16x32_bf16(a1, bf, acc1[1][nt], 0, 0, 0);
        }
    }
    #pragma unroll
    for (int mt = 0; mt < 2; ++mt)
        #pragma unroll
        for (int nt = 0; nt < 8; ++nt)
            #pragma unroll
            for (int r = 0; r < 4; ++r) {
                int row = mt * 16 + quad * 4 + r;
                int colh = wave * 128 + nt * 16 + l16;
                hid[row * HP + colh] = f2b(gelu_tanh(acc1[mt][nt][r]));
            }
    __syncthreads();

    f32x4 acc2[2][2];
    #pragma unroll
    for (int nt = 0; nt < 2; ++nt) {
        float bb = b2[wave * 32 + nt * 16 + l16];
        acc2[0][nt] = (f32x4){bb, bb, bb, bb};
        acc2[1][nt] = (f32x4){bb, bb, bb, bb};
    }
    #pragma unroll 4
    for (int kt = 0; kt < 16; ++kt) {
        int klane = kt * 32 + quad * 8;
        bf16x8 a0 = *(const bf16x8*)(hid + (l16)      * HP + klane);
        bf16x8 a1 = *(const bf16x8*)(hid + (16 + l16) * HP + klane);
        #pragma unroll
        for (int nt = 0; nt < 2; ++nt) {
            bf16x8 bf = *(const bf16x8*)(Wt2 + (size_t)(wave * 32 + nt * 16 + l16) * HID + klane);
            acc2[0][nt] = __builtin_amdgcn_mfma_f32_16x16x32_bf16(a0, bf, acc2[0][nt], 0, 0, 0);
            acc2[1][nt] = __builtin_amdgcn_mfma_f32_16x16x32_bf16(a1, bf, acc2[1][nt], 0, 0, 0);
        }
    }
    #pragma unroll
    for (int mt = 0; mt < 2; ++mt)
        #pragma unroll
        for (int nt = 0; nt < 2; ++nt)
            #pragma unroll
            for (int r = 0; r < 4; ++r) {
                int n = m0 + mt * 16 + quad * 4 + r;
                int c = wave * 32 + nt * 16 + l16;
                if (n < N)
                    out[(size_t)n * D + c] = ln[(size_t)n * D + c] + acc2[mt][nt][r];
            }
}

// ---------- launch ----------
extern "C" void kernel_launch(void* const* d_in, const int* in_sizes, int n_in,
                              void* d_out, int out_size, void* d_ws, size_t ws_size,
                              hipStream_t stream) {
    const float* x   = (const float*)d_in[0];
    const int*   ei  = (const int*)d_in[1];
    const float* Wq  = (const float*)d_in[2];
    const float* bq  = (const float*)d_in[3];
    const float* Wk  = (const float*)d_in[4];
    const float* bk  = (const float*)d_in[5];
    const float* Wv  = (const float*)d_in[6];
    const float* bv  = (const float*)d_in[7];
    const float* Wo  = (const float*)d_in[8];
    const float* bo  = (const float*)d_in[9];
    const float* lng = (const float*)d_in[10];
    const float* lnb = (const float*)d_in[11];
    const float* W1  = (const float*)d_in[12];
    const float* b1  = (const float*)d_in[13];
    const float* W2  = (const float*)d_in[14];
    const float* b2  = (const float*)d_in[15];
    float* out = (float*)d_out;

    int N = in_sizes[0] / D;
    int E = in_sizes[1] / 2;
    const int* srcp = ei;
    const int* dstp = ei + E;

    // workspace layout
    short* Wt1 = (short*)d_ws;                 // 512*128
    short* Wt2 = Wt1 + 512 * 128;              // 128*512
    short* Wtq = Wt2 + 512 * 128;              // 128*128
    short* Wtk = Wtq + 128 * 128;
    short* Wtv = Wtk + 128 * 128;
    float* q   = (float*)(Wtv + 128 * 128);    // N*D fp32
    short* kv  = (short*)(q + (size_t)N * D);  // N*256 bf16
    float* agg = (float*)(kv + (size_t)N * 256);
    float* lnout = agg + (size_t)N * D;
    int*   deg     = (int*)(lnout + (size_t)N * D);
    int*   row_ptr = deg + N;                  // N+1
    int*   cursor  = row_ptr + N + 1;
    int*   col     = cursor + N;               // E

    int nblk   = (N + NB - 1) / NB;
    int nblk32 = (N + MT - 1) / MT;
    int eblk   = (E + 255) / 256;

    k0_zero_deg<<<(N + 255) / 256, 256, 0, stream>>>(deg, N);
    k_prep<<<(512 * 128) / 256, 256, 0, stream>>>(W1, W2, Wq, Wk, Wv, Wt1, Wt2, Wtq, Wtk, Wtv);
    k_hist<<<eblk, 256, 0, stream>>>(dstp, deg, E);
    k1_qkv_mfma<<<nblk32, 256, 0, stream>>>(x, Wtq, bq, Wtk, bk, Wtv, bv, q, kv, N);
    k_scan<<<1, 1024, 0, stream>>>(deg, row_ptr, cursor, N);
    k_scatter<<<eblk, 256, 0, stream>>>(srcp, dstp, cursor, col, E);
    k_attn<<<(N + WPB - 1) / WPB, WPB * 64, 0, stream>>>(q, kv, row_ptr, col, agg, N);
    k5_wo_ln<<<nblk, D, 0, stream>>>(agg, Wo, bo, x, lng, lnb, lnout, N);
    k6_mlp_mfma<<<nblk32, 256, 0, stream>>>(lnout, Wt1, b1, Wt2, b2, out, N);
}

// Round 5
// 345.586 us; speedup vs baseline: 2.4438x; 1.2779x over previous
//
#include <hip/hip_runtime.h>
#include <math.h>

#define D   128
#define HH  4
#define HD  32
#define HID 512
#define WPB 4     // nodes (waves) per block in fused attention
#define MT  32    // node tile for MFMA kernels
#define XP  136   // 128+8 padded LDS row (bf16 elems)
#define HP  520   // 512+8 padded hidden row (bf16 elems)
#define KVP 264   // 256+8 padded kv LDS row (bf16 elems)
#define SCB 1024  // elems per scan block

typedef __attribute__((ext_vector_type(8))) short bf16x8;  // 8 bf16 (4 VGPRs)
typedef __attribute__((ext_vector_type(4))) float f32x4;   // MFMA C/D frag

// fp32 -> bf16 bits, round-to-nearest-even
__device__ __forceinline__ short f2b(float f) {
    unsigned u = __float_as_uint(f);
    unsigned r = (u + 0x7FFFu + ((u >> 16) & 1u)) >> 16;
    return (short)r;
}
__device__ __forceinline__ float b2f(short s) {
    return __uint_as_float(((unsigned)(unsigned short)s) << 16);
}

__device__ __forceinline__ float gelu_tanh(float x) {
    float x3 = x * x * x;
    float u = 0.7978845608028654f * (x + 0.044715f * x3);
    return 0.5f * x * (1.0f + tanhf(u));
}

// ---------- K0: zero degree array ----------
__global__ void k0_zero_deg(int* __restrict__ deg, int N) {
    int i = blockIdx.x * blockDim.x + threadIdx.x;
    if (i < N) deg[i] = 0;
}

// ---------- prep: all weights -> bf16 transposed [n][k] ----------
__global__ void k_prep(const float* __restrict__ W1, const float* __restrict__ W2,
                       const float* __restrict__ Wq, const float* __restrict__ Wk,
                       const float* __restrict__ Wv, const float* __restrict__ Wo,
                       short* __restrict__ Wt1, short* __restrict__ Wt2,
                       short* __restrict__ Wtq, short* __restrict__ Wtk,
                       short* __restrict__ Wtv, short* __restrict__ Wto) {
    int i = blockIdx.x * 256 + threadIdx.x;     // 65536 threads
    {   int n = i >> 7, k = i & 127; Wt1[i] = f2b(W1[k * HID + n]); }
    {   int n = i >> 9, k = i & 511; Wt2[i] = f2b(W2[k * D + n]); }
    if (i < D * D) {
        int n = i >> 7, k = i & 127;
        Wtq[i] = f2b(Wq[k * D + n]);
        Wtk[i] = f2b(Wk[k * D + n]);
        Wtv[i] = f2b(Wv[k * D + n]);
        Wto[i] = f2b(Wo[k * D + n]);
    }
}

// ---------- K1 (MFMA): q fp32, kv bf16 interleaved ----------
__global__ __launch_bounds__(256) void k1_qkv_mfma(
        const float* __restrict__ x,
        const short* __restrict__ Wtq, const float* __restrict__ bq,
        const short* __restrict__ Wtk, const float* __restrict__ bk,
        const short* __restrict__ Wtv, const float* __restrict__ bv,
        float* __restrict__ q, short* __restrict__ kv, int N) {
    __shared__ short xs[MT * XP];
    __shared__ short kvs[MT * KVP];
    int m0 = blockIdx.x * MT;
    int t = threadIdx.x;
    int wave = t >> 6, lane = t & 63, quad = lane >> 4, l16 = lane & 15;

    {
        int row = t >> 3, c0 = (t & 7) * 16;
        int n = m0 + row;
        #pragma unroll
        for (int c = 0; c < 16; c += 4) {
            float4 xv = {0.f, 0.f, 0.f, 0.f};
            if (n < N) xv = *(const float4*)(x + (size_t)n * D + c0 + c);
            xs[row * XP + c0 + c + 0] = f2b(xv.x);
            xs[row * XP + c0 + c + 1] = f2b(xv.y);
            xs[row * XP + c0 + c + 2] = f2b(xv.z);
            xs[row * XP + c0 + c + 3] = f2b(xv.w);
        }
    }
    __syncthreads();

    f32x4 accq[2][2], acck[2][2], accv[2][2];
    #pragma unroll
    for (int nt = 0; nt < 2; ++nt) {
        int c = wave * 32 + nt * 16 + l16;
        float q0 = bq[c], k0 = bk[c], v0 = bv[c];
        #pragma unroll
        for (int mt = 0; mt < 2; ++mt) {
            accq[mt][nt] = (f32x4){q0, q0, q0, q0};
            acck[mt][nt] = (f32x4){k0, k0, k0, k0};
            accv[mt][nt] = (f32x4){v0, v0, v0, v0};
        }
    }
    #pragma unroll
    for (int kt = 0; kt < 4; ++kt) {
        int klane = kt * 32 + quad * 8;
        bf16x8 a0 = *(const bf16x8*)(xs + (l16)      * XP + klane);
        bf16x8 a1 = *(const bf16x8*)(xs + (16 + l16) * XP + klane);
        #pragma unroll
        for (int nt = 0; nt < 2; ++nt) {
            int c = wave * 32 + nt * 16 + l16;
            bf16x8 fq = *(const bf16x8*)(Wtq + (size_t)c * D + klane);
            bf16x8 fk = *(const bf16x8*)(Wtk + (size_t)c * D + klane);
            bf16x8 fv = *(const bf16x8*)(Wtv + (size_t)c * D + klane);
            accq[0][nt] = __builtin_amdgcn_mfma_f32_16x16x32_bf16(a0, fq, accq[0][nt], 0, 0, 0);
            accq[1][nt] = __builtin_amdgcn_mfma_f32_16x16x32_bf16(a1, fq, accq[1][nt], 0, 0, 0);
            acck[0][nt] = __builtin_amdgcn_mfma_f32_16x16x32_bf16(a0, fk, acck[0][nt], 0, 0, 0);
            acck[1][nt] = __builtin_amdgcn_mfma_f32_16x16x32_bf16(a1, fk, acck[1][nt], 0, 0, 0);
            accv[0][nt] = __builtin_amdgcn_mfma_f32_16x16x32_bf16(a0, fv, accv[0][nt], 0, 0, 0);
            accv[1][nt] = __builtin_amdgcn_mfma_f32_16x16x32_bf16(a1, fv, accv[1][nt], 0, 0, 0);
        }
    }
    #pragma unroll
    for (int mt = 0; mt < 2; ++mt)
        #pragma unroll
        for (int nt = 0; nt < 2; ++nt)
            #pragma unroll
            for (int r = 0; r < 4; ++r) {
                int row = mt * 16 + quad * 4 + r;
                int n = m0 + row;
                int c = wave * 32 + nt * 16 + l16;
                if (n < N) q[(size_t)n * D + c] = accq[mt][nt][r];
                int base = row * KVP + (c >> 1) * 4 + (c & 1);
                kvs[base]     = f2b(acck[mt][nt][r]);
                kvs[base + 2] = f2b(accv[mt][nt][r]);
            }
    __syncthreads();
    {
        int row = t >> 3, c0 = (t & 7) * 32;
        int n = m0 + row;
        if (n < N) {
            #pragma unroll
            for (int i = 0; i < 4; ++i)
                *(uint4*)(kv + (size_t)n * 256 + c0 + i * 8) =
                    *(const uint4*)(kvs + row * KVP + c0 + i * 8);
        }
    }
}

// ---------- CSR build ----------
__global__ void k_hist(const int* __restrict__ dst, int* __restrict__ deg, int E) {
    int i = blockIdx.x * blockDim.x + threadIdx.x;
    if (i < E) atomicAdd(&deg[dst[i]], 1);
}

// scan phase 1: per-1024-chunk block sums
__global__ void k_scan1(const int* __restrict__ deg, int* __restrict__ partial, int N) {
    __shared__ int red[256];
    int b = blockIdx.x, t = threadIdx.x;
    int base = b * SCB + t * 4;
    int s = 0;
    #pragma unroll
    for (int i = 0; i < 4; ++i) { int idx = base + i; if (idx < N) s += deg[idx]; }
    red[t] = s;
    __syncthreads();
    for (int off = 128; off > 0; off >>= 1) {
        if (t < off) red[t] += red[t + off];
        __syncthreads();
    }
    if (t == 0) partial[b] = red[0];
}

// scan phase 2: exclusive scan of <=256 partials (single tiny block)
__global__ void k_scan2(int* __restrict__ partial, int nb) {
    __shared__ int s[256];
    int t = threadIdx.x;
    int v0 = (t < nb) ? partial[t] : 0;
    s[t] = v0;
    __syncthreads();
    for (int off = 1; off < 256; off <<= 1) {
        int v = (t >= off) ? s[t - off] : 0;
        __syncthreads();
        s[t] += v;
        __syncthreads();
    }
    if (t < nb) partial[t] = s[t] - v0;      // exclusive
    if (t == nb - 1) partial[nb] = s[t];     // grand total
}

// scan phase 3: re-scan chunk with block offset; write row_ptr + cursor
__global__ void k_scan3(const int* __restrict__ deg, const int* __restrict__ partial,
                        int* __restrict__ row_ptr, int* __restrict__ cursor,
                        int N, int nb) {
    __shared__ int red[256];
    int b = blockIdx.x, t = threadIdx.x;
    int base = b * SCB + t * 4;
    int d0[4]; int s = 0;
    #pragma unroll
    for (int i = 0; i < 4; ++i) {
        int idx = base + i;
        d0[i] = (idx < N) ? deg[idx] : 0;
        s += d0[i];
    }
    red[t] = s;
    __syncthreads();
    for (int off = 1; off < 256; off <<= 1) {
        int v = (t >= off) ? red[t - off] : 0;
        __syncthreads();
        red[t] += v;
        __syncthreads();
    }
    int off0 = partial[b] + red[t] - s;   // exclusive prefix for this thread
    #pragma unroll
    for (int i = 0; i < 4; ++i) {
        int idx = base + i;
        if (idx < N) { row_ptr[idx] = off0; cursor[idx] = off0; off0 += d0[i]; }
    }
    if (b == 0 && t == 0) row_ptr[N] = partial[nb];
}

__global__ void k_scatter(const int* __restrict__ src, const int* __restrict__ dst,
                          int* __restrict__ cursor, int* __restrict__ col, int E) {
    int i = blockIdx.x * blockDim.x + threadIdx.x;
    if (i < E) {
        int d = dst[i];
        int pos = atomicAdd(&cursor[d], 1);
        col[pos] = src[i];
    }
}

// ---------- fused attention: bf16 interleaved kv gather ----------
__global__ void k_attn(const float* __restrict__ q, const short* __restrict__ kv,
                       const int* __restrict__ row_ptr, const int* __restrict__ col,
                       float* __restrict__ agg, int N) {
    int wave = threadIdx.x >> 6;
    int lane = threadIdx.x & 63;
    int n = blockIdx.x * WPB + wave;
    if (n >= N) return;
    int beg = row_ptr[n], end = row_ptr[n + 1];

    float2 qv = *(const float2*)(q + (size_t)n * D + 2 * lane);

    float m = -INFINITY, l = 0.f;
    float2 acc = {0.f, 0.f};

    short4 cur;
    if (beg < end) {
        int s0 = col[beg];
        cur = *(const short4*)(kv + (size_t)s0 * 256 + 4 * lane);
    }
    for (int p = beg; p < end; ++p) {
        short4 ckv = cur;
        if (p + 1 < end) {
            int s1 = col[p + 1];
            cur = *(const short4*)(kv + (size_t)s1 * 256 + 4 * lane);
        }
        float kx = b2f(ckv.x), ky = b2f(ckv.y);
        float vx = b2f(ckv.z), vy = b2f(ckv.w);
        float part = qv.x * kx + qv.y * ky;
        part += __shfl_xor(part, 1);
        part += __shfl_xor(part, 2);
        part += __shfl_xor(part, 4);
        part += __shfl_xor(part, 8);
        float sc = part * 0.17677669529663687f;
        float mn = fmaxf(m, sc);
        float alpha = __expf(m - mn);
        float pe    = __expf(sc - mn);
        l = l * alpha + pe;
        acc.x = acc.x * alpha + pe * vx;
        acc.y = acc.y * alpha + pe * vy;
        m = mn;
    }
    float inv = (l > 0.f) ? 1.f / l : 0.f;
    float2 o = {acc.x * inv, acc.y * inv};
    *(float2*)(agg + (size_t)n * D + 2 * lane) = o;
}

// ---------- K5 (MFMA): lnout = LN(agg @ Wo + bo + x) ----------
// 32 nodes/block, 4 waves; wave owns out cols [wave*32,+32). LN epilogue in LDS.
__global__ __launch_bounds__(256) void k5_wo_ln_mfma(
        const float* __restrict__ agg, const short* __restrict__ Wto,
        const float* __restrict__ bo, const float* __restrict__ x,
        const float* __restrict__ g, const float* __restrict__ b,
        float* __restrict__ lnout, int N) {
    __shared__ short xs[MT * XP];          // agg tile bf16
    __shared__ float rowb[MT * 132];       // pre-LN rows fp32, padded
    __shared__ float ps[MT * 8], ps2[MT * 8];
    __shared__ float mu[MT], rstd[MT];
    int m0 = blockIdx.x * MT;
    int t = threadIdx.x;
    int wave = t >> 6, lane = t & 63, quad = lane >> 4, l16 = lane & 15;

    {
        int row = t >> 3, c0 = (t & 7) * 16;
        int n = m0 + row;
        #pragma unroll
        for (int c = 0; c < 16; c += 4) {
            float4 xv = {0.f, 0.f, 0.f, 0.f};
            if (n < N) xv = *(const float4*)(agg + (size_t)n * D + c0 + c);
            xs[row * XP + c0 + c + 0] = f2b(xv.x);
            xs[row * XP + c0 + c + 1] = f2b(xv.y);
            xs[row * XP + c0 + c + 2] = f2b(xv.z);
            xs[row * XP + c0 + c + 3] = f2b(xv.w);
        }
    }
    __syncthreads();

    f32x4 acc[2][2];
    #pragma unroll
    for (int nt = 0; nt < 2; ++nt) {
        float bb = bo[wave * 32 + nt * 16 + l16];
        acc[0][nt] = (f32x4){bb, bb, bb, bb};
        acc[1][nt] = (f32x4){bb, bb, bb, bb};
    }
    #pragma unroll
    for (int kt = 0; kt < 4; ++kt) {
        int klane = kt * 32 + quad * 8;
        bf16x8 a0 = *(const bf16x8*)(xs + (l16)      * XP + klane);
        bf16x8 a1 = *(const bf16x8*)(xs + (16 + l16) * XP + klane);
        #pragma unroll
        for (int nt = 0; nt < 2; ++nt) {
            bf16x8 bf = *(const bf16x8*)(Wto + (size_t)(wave * 32 + nt * 16 + l16) * D + klane);
            acc[0][nt] = __builtin_amdgcn_mfma_f32_16x16x32_bf16(a0, bf, acc[0][nt], 0, 0, 0);
            acc[1][nt] = __builtin_amdgcn_mfma_f32_16x16x32_bf16(a1, bf, acc[1][nt], 0, 0, 0);
        }
    }
    // + residual -> rowb
    #pragma unroll
    for (int mt = 0; mt < 2; ++mt)
        #pragma unroll
        for (int nt = 0; nt < 2; ++nt)
            #pragma unroll
            for (int r = 0; r < 4; ++r) {
                int row = mt * 16 + quad * 4 + r;
                int n = m0 + row;
                int c = wave * 32 + nt * 16 + l16;
                float val = acc[mt][nt][r];
                if (n < N) val += x[(size_t)n * D + c];
                rowb[row * 132 + c] = val;
            }
    __syncthreads();

    // stats: 8 threads per row
    int row = t >> 3, l8 = t & 7;
    float s1 = 0.f, s2 = 0.f;
    #pragma unroll
    for (int c = l8; c < D; c += 8) {
        float v = rowb[row * 132 + c];
        s1 += v; s2 += v * v;
    }
    ps[row * 8 + l8] = s1; ps2[row * 8 + l8] = s2;
    __syncthreads();
    if (l8 == 0) {
        float m = 0.f, m2 = 0.f;
        #pragma unroll
        for (int i = 0; i < 8; ++i) { m += ps[row * 8 + i]; m2 += ps2[row * 8 + i]; }
        m *= (1.0f / D); m2 *= (1.0f / D);
        mu[row] = m; rstd[row] = rsqrtf(m2 - m * m + 1e-5f);
    }
    __syncthreads();

    int n = m0 + row;
    if (n < N) {
        float mm = mu[row], rs = rstd[row];
        #pragma unroll
        for (int i = 0; i < 16; i += 4) {
            int c = l8 * 16 + i;
            float4 gg = *(const float4*)(g + c);
            float4 bb = *(const float4*)(b + c);
            float4 o;
            o.x = (rowb[row * 132 + c + 0] - mm) * rs * gg.x + bb.x;
            o.y = (rowb[row * 132 + c + 1] - mm) * rs * gg.y + bb.y;
            o.z = (rowb[row * 132 + c + 2] - mm) * rs * gg.z + bb.z;
            o.w = (rowb[row * 132 + c + 3] - mm) * rs * gg.w + bb.w;
            *(float4*)(lnout + (size_t)n * D + c) = o;
        }
    }
}

// ---------- K6 (MFMA): out = ln + gelu(ln@W1+b1)@W2+b2 ----------
__global__ __launch_bounds__(256) void k6_mlp_mfma(
        const float* __restrict__ ln, const short* __restrict__ Wt1,
        const float* __restrict__ b1, const short* __restrict__ Wt2,
        const float* __restrict__ b2, float* __restrict__ out, int N) {
    __shared__ short xs[MT * XP];
    __shared__ short hid[MT * HP];
    int m0 = blockIdx.x * MT;
    int t = threadIdx.x;
    int wave = t >> 6, lane = t & 63, quad = lane >> 4, l16 = lane & 15;

    {
        int row = t >> 3, c0 = (t & 7) * 16;
        int n = m0 + row;
        #pragma unroll
        for (int c = 0; c < 16; c += 4) {
            float4 xv = {0.f, 0.f, 0.f, 0.f};
            if (n < N) xv = *(const float4*)(ln + (size_t)n * D + c0 + c);
            xs[row * XP + c0 + c + 0] = f2b(xv.x);
            xs[row * XP + c0 + c + 1] = f2b(xv.y);
            xs[row * XP + c0 + c + 2] = f2b(xv.z);
            xs[row * XP + c0 + c + 3] = f2b(xv.w);
        }
    }
    __syncthreads();

    f32x4 acc1[2][8];
    #pragma unroll
    for (int nt = 0; nt < 8; ++nt) {
        float bb = b1[wave * 128 + nt * 16 + l16];
        acc1[0][nt] = (f32x4){bb, bb, bb, bb};
        acc1[1][nt] = (f32x4){bb, bb, bb, bb};
    }
    #pragma unroll
    for (int kt = 0; kt < 4; ++kt) {
        int klane = kt * 32 + quad * 8;
        bf16x8 a0 = *(const bf16x8*)(xs + (l16)      * XP + klane);
        bf16x8 a1 = *(const bf16x8*)(xs + (16 + l16) * XP + klane);
        #pragma unroll
        for (int nt = 0; nt < 8; ++nt) {
            bf16x8 bf = *(const bf16x8*)(Wt1 + (size_t)(wave * 128 + nt * 16 + l16) * D + klane);
            acc1[0][nt] = __builtin_amdgcn_mfma_f32_16x16x32_bf16(a0, bf, acc1[0][nt], 0, 0, 0);
            acc1[1][nt] = __builtin_amdgcn_mfma_f32_16x16x32_bf16(a1, bf, acc1[1][nt], 0, 0, 0);
        }
    }
    #pragma unroll
    for (int mt = 0; mt < 2; ++mt)
        #pragma unroll
        for (int nt = 0; nt < 8; ++nt)
            #pragma unroll
            for (int r = 0; r < 4; ++r) {
                int row = mt * 16 + quad * 4 + r;
                int colh = wave * 128 + nt * 16 + l16;
                hid[row * HP + colh] = f2b(gelu_tanh(acc1[mt][nt][r]));
            }
    __syncthreads();

    f32x4 acc2[2][2];
    #pragma unroll
    for (int nt = 0; nt < 2; ++nt) {
        float bb = b2[wave * 32 + nt * 16 + l16];
        acc2[0][nt] = (f32x4){bb, bb, bb, bb};
        acc2[1][nt] = (f32x4){bb, bb, bb, bb};
    }
    #pragma unroll 4
    for (int kt = 0; kt < 16; ++kt) {
        int klane = kt * 32 + quad * 8;
        bf16x8 a0 = *(const bf16x8*)(hid + (l16)      * HP + klane);
        bf16x8 a1 = *(const bf16x8*)(hid + (16 + l16) * HP + klane);
        #pragma unroll
        for (int nt = 0; nt < 2; ++nt) {
            bf16x8 bf = *(const bf16x8*)(Wt2 + (size_t)(wave * 32 + nt * 16 + l16) * HID + klane);
            acc2[0][nt] = __builtin_amdgcn_mfma_f32_16x16x32_bf16(a0, bf, acc2[0][nt], 0, 0, 0);
            acc2[1][nt] = __builtin_amdgcn_mfma_f32_16x16x32_bf16(a1, bf, acc2[1][nt], 0, 0, 0);
        }
    }
    #pragma unroll
    for (int mt = 0; mt < 2; ++mt)
        #pragma unroll
        for (int nt = 0; nt < 2; ++nt)
            #pragma unroll
            for (int r = 0; r < 4; ++r) {
                int n = m0 + mt * 16 + quad * 4 + r;
                int c = wave * 32 + nt * 16 + l16;
                if (n < N)
                    out[(size_t)n * D + c] = ln[(size_t)n * D + c] + acc2[mt][nt][r];
            }
}

// ---------- launch ----------
extern "C" void kernel_launch(void* const* d_in, const int* in_sizes, int n_in,
                              void* d_out, int out_size, void* d_ws, size_t ws_size,
                              hipStream_t stream) {
    const float* x   = (const float*)d_in[0];
    const int*   ei  = (const int*)d_in[1];
    const float* Wq  = (const float*)d_in[2];
    const float* bq  = (const float*)d_in[3];
    const float* Wk  = (const float*)d_in[4];
    const float* bk  = (const float*)d_in[5];
    const float* Wv  = (const float*)d_in[6];
    const float* bv  = (const float*)d_in[7];
    const float* Wo  = (const float*)d_in[8];
    const float* bo  = (const float*)d_in[9];
    const float* lng = (const float*)d_in[10];
    const float* lnb = (const float*)d_in[11];
    const float* W1  = (const float*)d_in[12];
    const float* b1  = (const float*)d_in[13];
    const float* W2  = (const float*)d_in[14];
    const float* b2  = (const float*)d_in[15];
    float* out = (float*)d_out;

    int N = in_sizes[0] / D;
    int E = in_sizes[1] / 2;
    const int* srcp = ei;
    const int* dstp = ei + E;

    // workspace layout
    short* Wt1 = (short*)d_ws;                 // 512*128
    short* Wt2 = Wt1 + 512 * 128;              // 128*512
    short* Wtq = Wt2 + 512 * 128;              // 128*128
    short* Wtk = Wtq + 128 * 128;
    short* Wtv = Wtk + 128 * 128;
    short* Wto = Wtv + 128 * 128;
    float* q   = (float*)(Wto + 128 * 128);    // N*D fp32
    short* kv  = (short*)(q + (size_t)N * D);  // N*256 bf16
    float* agg = (float*)(kv + (size_t)N * 256);
    float* lnout = agg + (size_t)N * D;
    int*   deg     = (int*)(lnout + (size_t)N * D);
    int*   row_ptr = deg + N;                  // N+1
    int*   cursor  = row_ptr + N + 1;
    int*   col     = cursor + N;               // E
    int*   partial = col + E;                  // nbs+1

    int nblk32 = (N + MT - 1) / MT;
    int eblk   = (E + 255) / 256;
    int nbs    = (N + SCB - 1) / SCB;

    k0_zero_deg<<<(N + 255) / 256, 256, 0, stream>>>(deg, N);
    k_prep<<<(512 * 128) / 256, 256, 0, stream>>>(W1, W2, Wq, Wk, Wv, Wo,
                                                  Wt1, Wt2, Wtq, Wtk, Wtv, Wto);
    k_hist<<<eblk, 256, 0, stream>>>(dstp, deg, E);
    k1_qkv_mfma<<<nblk32, 256, 0, stream>>>(x, Wtq, bq, Wtk, bk, Wtv, bv, q, kv, N);
    k_scan1<<<nbs, 256, 0, stream>>>(deg, partial, N);
    k_scan2<<<1, 256, 0, stream>>>(partial, nbs);
    k_scan3<<<nbs, 256, 0, stream>>>(deg, partial, row_ptr, cursor, N, nbs);
    k_scatter<<<eblk, 256, 0, stream>>>(srcp, dstp, cursor, col, E);
    k_attn<<<(N + WPB - 1) / WPB, WPB * 64, 0, stream>>>(q, kv, row_ptr, col, agg, N);
    k5_wo_ln_mfma<<<nblk32, 256, 0, stream>>>(agg, Wto, bo, x, lng, lnb, lnout, N);
    k6_mlp_mfma<<<nblk32, 256, 0, stream>>>(lnout, Wt1, b1, Wt2, b2, out, N);
}

// Round 6
// 339.682 us; speedup vs baseline: 2.4863x; 1.0174x over previous
//
#include <hip/hip_runtime.h>
#include <math.h>

#define D   128
#define HH  4
#define HD  32
#define HID 512
#define WPB 4     // nodes (waves) per block in fused attention
#define MT  32    // node tile for MFMA kernels
#define XP  136   // 128+8 padded LDS row (bf16 elems)
#define HP  520   // 512+8 padded hidden row (bf16 elems)
#define KVB 264   // 256+8 padded kv LDS row (bytes)
#define SCB 1024  // elems per scan block

typedef __attribute__((ext_vector_type(8))) short bf16x8;  // 8 bf16 (4 VGPRs)
typedef __attribute__((ext_vector_type(4))) float f32x4;   // MFMA C/D frag
typedef __attribute__((ext_vector_type(2))) float f32x2;

// fp32 -> bf16 bits, round-to-nearest-even
__device__ __forceinline__ short f2b(float f) {
    unsigned u = __float_as_uint(f);
    unsigned r = (u + 0x7FFFu + ((u >> 16) & 1u)) >> 16;
    return (short)r;
}
// fp32 -> fp8 e4m3 (OCP on gfx950), via hw packed cvt
__device__ __forceinline__ unsigned char f2fp8(float f) {
    return (unsigned char)(__builtin_amdgcn_cvt_pk_fp8_f32(f, f, 0, false) & 0xFF);
}

__device__ __forceinline__ float gelu_tanh(float x) {
    float x3 = x * x * x;
    float u = 0.7978845608028654f * (x + 0.044715f * x3);
    return 0.5f * x * (1.0f + tanhf(u));
}

// ---------- K0: zero degree array ----------
__global__ void k0_zero_deg(int* __restrict__ deg, int N) {
    int i = blockIdx.x * blockDim.x + threadIdx.x;
    if (i < N) deg[i] = 0;
}

// ---------- prep: all weights -> bf16 transposed [n][k] ----------
__global__ void k_prep(const float* __restrict__ W1, const float* __restrict__ W2,
                       const float* __restrict__ Wq, const float* __restrict__ Wk,
                       const float* __restrict__ Wv, const float* __restrict__ Wo,
                       short* __restrict__ Wt1, short* __restrict__ Wt2,
                       short* __restrict__ Wtq, short* __restrict__ Wtk,
                       short* __restrict__ Wtv, short* __restrict__ Wto) {
    int i = blockIdx.x * 256 + threadIdx.x;     // 65536 threads
    {   int n = i >> 7, k = i & 127; Wt1[i] = f2b(W1[k * HID + n]); }
    {   int n = i >> 9, k = i & 511; Wt2[i] = f2b(W2[k * D + n]); }
    if (i < D * D) {
        int n = i >> 7, k = i & 127;
        Wtq[i] = f2b(Wq[k * D + n]);
        Wtk[i] = f2b(Wk[k * D + n]);
        Wtv[i] = f2b(Wv[k * D + n]);
        Wto[i] = f2b(Wo[k * D + n]);
    }
}

// ---------- K1 (MFMA): q fp32, kv fp8 interleaved ----------
// kv row (256 B): byte (c>>1)*4 + (c&1) = k[c]; +2 = v[c]  (c = 0..127)
__global__ __launch_bounds__(256) void k1_qkv_mfma(
        const float* __restrict__ x,
        const short* __restrict__ Wtq, const float* __restrict__ bq,
        const short* __restrict__ Wtk, const float* __restrict__ bk,
        const short* __restrict__ Wtv, const float* __restrict__ bv,
        float* __restrict__ q, unsigned char* __restrict__ kv, int N) {
    __shared__ short xs[MT * XP];
    __shared__ unsigned char kvs[MT * KVB];
    int m0 = blockIdx.x * MT;
    int t = threadIdx.x;
    int wave = t >> 6, lane = t & 63, quad = lane >> 4, l16 = lane & 15;

    {
        int row = t >> 3, c0 = (t & 7) * 16;
        int n = m0 + row;
        #pragma unroll
        for (int c = 0; c < 16; c += 4) {
            float4 xv = {0.f, 0.f, 0.f, 0.f};
            if (n < N) xv = *(const float4*)(x + (size_t)n * D + c0 + c);
            xs[row * XP + c0 + c + 0] = f2b(xv.x);
            xs[row * XP + c0 + c + 1] = f2b(xv.y);
            xs[row * XP + c0 + c + 2] = f2b(xv.z);
            xs[row * XP + c0 + c + 3] = f2b(xv.w);
        }
    }
    __syncthreads();

    f32x4 accq[2][2], acck[2][2], accv[2][2];
    #pragma unroll
    for (int nt = 0; nt < 2; ++nt) {
        int c = wave * 32 + nt * 16 + l16;
        float q0 = bq[c], k0 = bk[c], v0 = bv[c];
        #pragma unroll
        for (int mt = 0; mt < 2; ++mt) {
            accq[mt][nt] = (f32x4){q0, q0, q0, q0};
            acck[mt][nt] = (f32x4){k0, k0, k0, k0};
            accv[mt][nt] = (f32x4){v0, v0, v0, v0};
        }
    }
    #pragma unroll
    for (int kt = 0; kt < 4; ++kt) {
        int klane = kt * 32 + quad * 8;
        bf16x8 a0 = *(const bf16x8*)(xs + (l16)      * XP + klane);
        bf16x8 a1 = *(const bf16x8*)(xs + (16 + l16) * XP + klane);
        #pragma unroll
        for (int nt = 0; nt < 2; ++nt) {
            int c = wave * 32 + nt * 16 + l16;
            bf16x8 fq = *(const bf16x8*)(Wtq + (size_t)c * D + klane);
            bf16x8 fk = *(const bf16x8*)(Wtk + (size_t)c * D + klane);
            bf16x8 fv = *(const bf16x8*)(Wtv + (size_t)c * D + klane);
            accq[0][nt] = __builtin_amdgcn_mfma_f32_16x16x32_bf16(a0, fq, accq[0][nt], 0, 0, 0);
            accq[1][nt] = __builtin_amdgcn_mfma_f32_16x16x32_bf16(a1, fq, accq[1][nt], 0, 0, 0);
            acck[0][nt] = __builtin_amdgcn_mfma_f32_16x16x32_bf16(a0, fk, acck[0][nt], 0, 0, 0);
            acck[1][nt] = __builtin_amdgcn_mfma_f32_16x16x32_bf16(a1, fk, acck[1][nt], 0, 0, 0);
            accv[0][nt] = __builtin_amdgcn_mfma_f32_16x16x32_bf16(a0, fv, accv[0][nt], 0, 0, 0);
            accv[1][nt] = __builtin_amdgcn_mfma_f32_16x16x32_bf16(a1, fv, accv[1][nt], 0, 0, 0);
        }
    }
    #pragma unroll
    for (int mt = 0; mt < 2; ++mt)
        #pragma unroll
        for (int nt = 0; nt < 2; ++nt)
            #pragma unroll
            for (int r = 0; r < 4; ++r) {
                int row = mt * 16 + quad * 4 + r;
                int n = m0 + row;
                int c = wave * 32 + nt * 16 + l16;
                if (n < N) q[(size_t)n * D + c] = accq[mt][nt][r];
                int base = row * KVB + (c >> 1) * 4 + (c & 1);
                kvs[base]     = f2fp8(acck[mt][nt][r]);
                kvs[base + 2] = f2fp8(accv[mt][nt][r]);
            }
    __syncthreads();
    {   // coop write-out: 8 threads per row, 32 B each
        int row = t >> 3, c0 = (t & 7) * 32;
        int n = m0 + row;
        if (n < N) {
            *(uint4*)(kv + (size_t)n * 256 + c0) =
                *(const uint4*)(kvs + row * KVB + c0);
            *(uint4*)(kv + (size_t)n * 256 + c0 + 16) =
                *(const uint4*)(kvs + row * KVB + c0 + 16);
        }
    }
}

// ---------- CSR build ----------
__global__ void k_hist(const int* __restrict__ dst, int* __restrict__ deg, int E) {
    int i = blockIdx.x * blockDim.x + threadIdx.x;
    if (i < E) atomicAdd(&deg[dst[i]], 1);
}

__global__ void k_scan1(const int* __restrict__ deg, int* __restrict__ partial, int N) {
    __shared__ int red[256];
    int b = blockIdx.x, t = threadIdx.x;
    int base = b * SCB + t * 4;
    int s = 0;
    #pragma unroll
    for (int i = 0; i < 4; ++i) { int idx = base + i; if (idx < N) s += deg[idx]; }
    red[t] = s;
    __syncthreads();
    for (int off = 128; off > 0; off >>= 1) {
        if (t < off) red[t] += red[t + off];
        __syncthreads();
    }
    if (t == 0) partial[b] = red[0];
}

__global__ void k_scan2(int* __restrict__ partial, int nb) {
    __shared__ int s[256];
    int t = threadIdx.x;
    int v0 = (t < nb) ? partial[t] : 0;
    s[t] = v0;
    __syncthreads();
    for (int off = 1; off < 256; off <<= 1) {
        int v = (t >= off) ? s[t - off] : 0;
        __syncthreads();
        s[t] += v;
        __syncthreads();
    }
    if (t < nb) partial[t] = s[t] - v0;
    if (t == nb - 1) partial[nb] = s[t];
}

__global__ void k_scan3(const int* __restrict__ deg, const int* __restrict__ partial,
                        int* __restrict__ row_ptr, int* __restrict__ cursor,
                        int N, int nb) {
    __shared__ int red[256];
    int b = blockIdx.x, t = threadIdx.x;
    int base = b * SCB + t * 4;
    int d0[4]; int s = 0;
    #pragma unroll
    for (int i = 0; i < 4; ++i) {
        int idx = base + i;
        d0[i] = (idx < N) ? deg[idx] : 0;
        s += d0[i];
    }
    red[t] = s;
    __syncthreads();
    for (int off = 1; off < 256; off <<= 1) {
        int v = (t >= off) ? red[t - off] : 0;
        __syncthreads();
        red[t] += v;
        __syncthreads();
    }
    int off0 = partial[b] + red[t] - s;
    #pragma unroll
    for (int i = 0; i < 4; ++i) {
        int idx = base + i;
        if (idx < N) { row_ptr[idx] = off0; cursor[idx] = off0; off0 += d0[i]; }
    }
    if (b == 0 && t == 0) row_ptr[N] = partial[nb];
}

__global__ void k_scatter(const int* __restrict__ src, const int* __restrict__ dst,
                          int* __restrict__ cursor, int* __restrict__ col, int E) {
    int i = blockIdx.x * blockDim.x + threadIdx.x;
    if (i < E) {
        int d = dst[i];
        int pos = atomicAdd(&cursor[d], 1);
        col[pos] = src[i];
    }
}

// ---------- fused attention: fp8 kv gather, no-max softmax (|score| < 1) ----------
__global__ void k_attn(const float* __restrict__ q, const unsigned char* __restrict__ kv,
                       const int* __restrict__ row_ptr, const int* __restrict__ col,
                       float* __restrict__ agg, int N) {
    int wave = threadIdx.x >> 6;
    int lane = threadIdx.x & 63;
    int n = blockIdx.x * WPB + wave;
    if (n >= N) return;
    int beg = row_ptr[n], end = row_ptr[n + 1];

    float2 qv = *(const float2*)(q + (size_t)n * D + 2 * lane);

    float l = 0.f;
    float2 acc = {0.f, 0.f};

    unsigned pk_cur = 0;
    int sB = 0;
    if (beg < end) {
        int sA = col[beg];
        pk_cur = *(const unsigned*)(kv + (size_t)sA * 256 + 4 * lane);
    }
    if (beg + 1 < end) sB = col[beg + 1];

    for (int p = beg; p < end; ++p) {
        unsigned pk = pk_cur;
        int sC = (p + 2 < end) ? col[p + 2] : 0;       // col prefetch depth-2
        if (p + 1 < end)
            pk_cur = *(const unsigned*)(kv + (size_t)sB * 256 + 4 * lane);
        sB = sC;

        f32x2 kp = __builtin_amdgcn_cvt_pk_f32_fp8((int)pk, false);
        f32x2 vp = __builtin_amdgcn_cvt_pk_f32_fp8((int)pk, true);
        float part = qv.x * kp.x + qv.y * kp.y;
        part += __shfl_xor(part, 1);
        part += __shfl_xor(part, 2);
        part += __shfl_xor(part, 4);
        part += __shfl_xor(part, 8);                    // 16-lane head reduce
        float pe = __expf(part * 0.17677669529663687f); // scores bounded: no max needed
        l += pe;
        acc.x = fmaf(pe, vp.x, acc.x);
        acc.y = fmaf(pe, vp.y, acc.y);
    }
    float inv = (l > 0.f) ? 1.f / l : 0.f;
    float2 o = {acc.x * inv, acc.y * inv};
    *(float2*)(agg + (size_t)n * D + 2 * lane) = o;
}

// ---------- K56 (fused MFMA): ln = LN(agg@Wo+bo+x); out = ln + gelu(ln@W1+b1)@W2+b2 ----------
__global__ __launch_bounds__(256) void k56_wo_ln_mlp(
        const float* __restrict__ agg, const short* __restrict__ Wto,
        const float* __restrict__ bo, const float* __restrict__ x,
        const float* __restrict__ g, const float* __restrict__ b,
        const short* __restrict__ Wt1, const float* __restrict__ b1,
        const short* __restrict__ Wt2, const float* __restrict__ b2,
        float* __restrict__ out, int N) {
    __shared__ short xs[MT * XP];          // agg tile bf16, later ln tile bf16
    __shared__ float rowb[MT * 132];       // fp32 rows (pre-LN, then ln)
    __shared__ short hid[MT * HP];         // hidden bf16
    __shared__ float ps[MT * 8], ps2[MT * 8];
    __shared__ float mu[MT], rstd[MT];
    int m0 = blockIdx.x * MT;
    int t = threadIdx.x;
    int wave = t >> 6, lane = t & 63, quad = lane >> 4, l16 = lane & 15;
    int row8 = t >> 3, l8 = t & 7;

    // stage agg -> xs bf16
    #pragma unroll
    for (int c = 0; c < 16; c += 4) {
        int n = m0 + row8, c0 = l8 * 16;
        float4 xv = {0.f, 0.f, 0.f, 0.f};
        if (n < N) xv = *(const float4*)(agg + (size_t)n * D + c0 + c);
        xs[row8 * XP + c0 + c + 0] = f2b(xv.x);
        xs[row8 * XP + c0 + c + 1] = f2b(xv.y);
        xs[row8 * XP + c0 + c + 2] = f2b(xv.z);
        xs[row8 * XP + c0 + c + 3] = f2b(xv.w);
    }
    __syncthreads();

    // phase A: Wo GEMM + residual
    f32x4 acc[2][2];
    #pragma unroll
    for (int nt = 0; nt < 2; ++nt) {
        float bb = bo[wave * 32 + nt * 16 + l16];
        acc[0][nt] = (f32x4){bb, bb, bb, bb};
        acc[1][nt] = (f32x4){bb, bb, bb, bb};
    }
    #pragma unroll
    for (int kt = 0; kt < 4; ++kt) {
        int klane = kt * 32 + quad * 8;
        bf16x8 a0 = *(const bf16x8*)(xs + (l16)      * XP + klane);
        bf16x8 a1 = *(const bf16x8*)(xs + (16 + l16) * XP + klane);
        #pragma unroll
        for (int nt = 0; nt < 2; ++nt) {
            bf16x8 bf = *(const bf16x8*)(Wto + (size_t)(wave * 32 + nt * 16 + l16) * D + klane);
            acc[0][nt] = __builtin_amdgcn_mfma_f32_16x16x32_bf16(a0, bf, acc[0][nt], 0, 0, 0);
            acc[1][nt] = __builtin_amdgcn_mfma_f32_16x16x32_bf16(a1, bf, acc[1][nt], 0, 0, 0);
        }
    }
    #pragma unroll
    for (int mt = 0; mt < 2; ++mt)
        #pragma unroll
        for (int nt = 0; nt < 2; ++nt)
            #pragma unroll
            for (int r = 0; r < 4; ++r) {
                int row = mt * 16 + quad * 4 + r;
                int n = m0 + row;
                int c = wave * 32 + nt * 16 + l16;
                float val = acc[mt][nt][r];
                if (n < N) val += x[(size_t)n * D + c];
                rowb[row * 132 + c] = val;
            }
    __syncthreads();

    // LN stats: 8 threads per row
    {
        float s1 = 0.f, s2 = 0.f;
        #pragma unroll
        for (int c = l8; c < D; c += 8) {
            float v = rowb[row8 * 132 + c];
            s1 += v; s2 += v * v;
        }
        ps[row8 * 8 + l8] = s1; ps2[row8 * 8 + l8] = s2;
    }
    __syncthreads();
    if (l8 == 0) {
        float m = 0.f, m2 = 0.f;
        #pragma unroll
        for (int i = 0; i < 8; ++i) { m += ps[row8 * 8 + i]; m2 += ps2[row8 * 8 + i]; }
        m *= (1.0f / D); m2 *= (1.0f / D);
        mu[row8] = m; rstd[row8] = rsqrtf(m2 - m * m + 1e-5f);
    }
    __syncthreads();
    // LN apply: rowb <- ln (fp32), xs <- ln (bf16)
    {
        float mm = mu[row8], rs = rstd[row8];
        #pragma unroll
        for (int i = 0; i < 16; ++i) {
            int c = l8 * 16 + i;
            float val = (rowb[row8 * 132 + c] - mm) * rs * g[c] + b[c];
            rowb[row8 * 132 + c] = val;
            xs[row8 * XP + c] = f2b(val);
        }
    }
    __syncthreads();

    // phase B1: hidden = gelu(ln @ W1 + b1)
    f32x4 acc1[2][8];
    #pragma unroll
    for (int nt = 0; nt < 8; ++nt) {
        float bb = b1[wave * 128 + nt * 16 + l16];
        acc1[0][nt] = (f32x4){bb, bb, bb, bb};
        acc1[1][nt] = (f32x4){bb, bb, bb, bb};
    }
    #pragma unroll
    for (int kt = 0; kt < 4; ++kt) {
        int klane = kt * 32 + quad * 8;
        bf16x8 a0 = *(const bf16x8*)(xs + (l16)      * XP + klane);
        bf16x8 a1 = *(const bf16x8*)(xs + (16 + l16) * XP + klane);
        #pragma unroll
        for (int nt = 0; nt < 8; ++nt) {
            bf16x8 bf = *(const bf16x8*)(Wt1 + (size_t)(wave * 128 + nt * 16 + l16) * D + klane);
            acc1[0][nt] = __builtin_amdgcn_mfma_f32_16x16x32_bf16(a0, bf, acc1[0][nt], 0, 0, 0);
            acc1[1][nt] = __builtin_amdgcn_mfma_f32_16x16x32_bf16(a1, bf, acc1[1][nt], 0, 0, 0);
        }
    }
    #pragma unroll
    for (int mt = 0; mt < 2; ++mt)
        #pragma unroll
        for (int nt = 0; nt < 8; ++nt)
            #pragma unroll
            for (int r = 0; r < 4; ++r) {
                int row = mt * 16 + quad * 4 + r;
                int colh = wave * 128 + nt * 16 + l16;
                hid[row * HP + colh] = f2b(gelu_tanh(acc1[mt][nt][r]));
            }
    __syncthreads();

    // phase B2: out = ln + hid @ W2 + b2
    f32x4 acc2[2][2];
    #pragma unroll
    for (int nt = 0; nt < 2; ++nt) {
        float bb = b2[wave * 32 + nt * 16 + l16];
        acc2[0][nt] = (f32x4){bb, bb, bb, bb};
        acc2[1][nt] = (f32x4){bb, bb, bb, bb};
    }
    #pragma unroll 4
    for (int kt = 0; kt < 16; ++kt) {
        int klane = kt * 32 + quad * 8;
        bf16x8 a0 = *(const bf16x8*)(hid + (l16)      * HP + klane);
        bf16x8 a1 = *(const bf16x8*)(hid + (16 + l16) * HP + klane);
        #pragma unroll
        for (int nt = 0; nt < 2; ++nt) {
            bf16x8 bf = *(const bf16x8*)(Wt2 + (size_t)(wave * 32 + nt * 16 + l16) * HID + klane);
            acc2[0][nt] = __builtin_amdgcn_mfma_f32_16x16x32_bf16(a0, bf, acc2[0][nt], 0, 0, 0);
            acc2[1][nt] = __builtin_amdgcn_mfma_f32_16x16x32_bf16(a1, bf, acc2[1][nt], 0, 0, 0);
        }
    }
    #pragma unroll
    for (int mt = 0; mt < 2; ++mt)
        #pragma unroll
        for (int nt = 0; nt < 2; ++nt)
            #pragma unroll
            for (int r = 0; r < 4; ++r) {
                int row = mt * 16 + quad * 4 + r;
                int n = m0 + row;
                int c = wave * 32 + nt * 16 + l16;
                if (n < N)
                    out[(size_t)n * D + c] = rowb[row * 132 + c] + acc2[mt][nt][r];
            }
}

// ---------- launch ----------
extern "C" void kernel_launch(void* const* d_in, const int* in_sizes, int n_in,
                              void* d_out, int out_size, void* d_ws, size_t ws_size,
                              hipStream_t stream) {
    const float* x   = (const float*)d_in[0];
    const int*   ei  = (const int*)d_in[1];
    const float* Wq  = (const float*)d_in[2];
    const float* bq  = (const float*)d_in[3];
    const float* Wk  = (const float*)d_in[4];
    const float* bk  = (const float*)d_in[5];
    const float* Wv  = (const float*)d_in[6];
    const float* bv  = (const float*)d_in[7];
    const float* Wo  = (const float*)d_in[8];
    const float* bo  = (const float*)d_in[9];
    const float* lng = (const float*)d_in[10];
    const float* lnb = (const float*)d_in[11];
    const float* W1  = (const float*)d_in[12];
    const float* b1  = (const float*)d_in[13];
    const float* W2  = (const float*)d_in[14];
    const float* b2  = (const float*)d_in[15];
    float* out = (float*)d_out;

    int N = in_sizes[0] / D;
    int E = in_sizes[1] / 2;
    const int* srcp = ei;
    const int* dstp = ei + E;

    // workspace layout
    short* Wt1 = (short*)d_ws;                 // 512*128
    short* Wt2 = Wt1 + 512 * 128;              // 128*512
    short* Wtq = Wt2 + 512 * 128;              // 128*128
    short* Wtk = Wtq + 128 * 128;
    short* Wtv = Wtk + 128 * 128;
    short* Wto = Wtv + 128 * 128;
    float* q   = (float*)(Wto + 128 * 128);    // N*D fp32
    unsigned char* kv = (unsigned char*)(q + (size_t)N * D);  // N*256 bytes fp8
    float* agg = (float*)(kv + (size_t)N * 256);
    int*   deg     = (int*)(agg + (size_t)N * D);
    int*   row_ptr = deg + N;                  // N+1
    int*   cursor  = row_ptr + N + 1;
    int*   col     = cursor + N;               // E
    int*   partial = col + E;                  // nbs+1

    int nblk32 = (N + MT - 1) / MT;
    int eblk   = (E + 255) / 256;
    int nbs    = (N + SCB - 1) / SCB;

    k0_zero_deg<<<(N + 255) / 256, 256, 0, stream>>>(deg, N);
    k_prep<<<(512 * 128) / 256, 256, 0, stream>>>(W1, W2, Wq, Wk, Wv, Wo,
                                                  Wt1, Wt2, Wtq, Wtk, Wtv, Wto);
    k_hist<<<eblk, 256, 0, stream>>>(dstp, deg, E);
    k1_qkv_mfma<<<nblk32, 256, 0, stream>>>(x, Wtq, bq, Wtk, bk, Wtv, bv, q, kv, N);
    k_scan1<<<nbs, 256, 0, stream>>>(deg, partial, N);
    k_scan2<<<1, 256, 0, stream>>>(partial, nbs);
    k_scan3<<<nbs, 256, 0, stream>>>(deg, partial, row_ptr, cursor, N, nbs);
    k_scatter<<<eblk, 256, 0, stream>>>(srcp, dstp, cursor, col, E);
    k_attn<<<(N + WPB - 1) / WPB, WPB * 64, 0, stream>>>(q, kv, row_ptr, col, agg, N);
    k56_wo_ln_mlp<<<nblk32, 256, 0, stream>>>(agg, Wto, bo, x, lng, lnb,
                                              Wt1, b1, Wt2, b2, out, N);
}

// Round 7
// 317.254 us; speedup vs baseline: 2.6620x; 1.0707x over previous
//
#include <hip/hip_runtime.h>
#include <math.h>

#define D   128
#define HH  4
#define HD  32
#define HID 512
#define WPB 4     // nodes (waves) per block in fused attention
#define MT  32    // node tile for MFMA kernels
#define XP  136   // 128+8 padded LDS row (bf16 elems)
#define HHP 264   // 256+8 padded half-hidden row (bf16 elems)
#define KVB 264   // 256+8 padded kv LDS row (bytes)
#define SCB 1024  // elems per scan block

typedef __attribute__((ext_vector_type(8))) short bf16x8;  // 8 bf16 (4 VGPRs)
typedef __attribute__((ext_vector_type(4))) float f32x4;   // MFMA C/D frag
typedef __attribute__((ext_vector_type(2))) float f32x2;

// fp32 -> bf16 bits, round-to-nearest-even
__device__ __forceinline__ short f2b(float f) {
    unsigned u = __float_as_uint(f);
    unsigned r = (u + 0x7FFFu + ((u >> 16) & 1u)) >> 16;
    return (short)r;
}
// fp32 -> fp8 e4m3 (OCP on gfx950), via hw packed cvt
__device__ __forceinline__ unsigned char f2fp8(float f) {
    return (unsigned char)(__builtin_amdgcn_cvt_pk_fp8_f32(f, f, 0, false) & 0xFF);
}

// gelu tanh-approx via hw exp: 0.5x(1+tanh u) = x*e^{2u}/(e^{2u}+1)
__device__ __forceinline__ float gelu_tanh(float x) {
    float u = 0.7978845608028654f * (x + 0.044715f * x * x * x);
    float e = __expf(2.0f * u);
    return x * e * __builtin_amdgcn_rcpf(e + 1.0f);
}

// ---------- K0: zero degree array ----------
__global__ void k0_zero_deg(int* __restrict__ deg, int N) {
    int i = blockIdx.x * blockDim.x + threadIdx.x;
    if (i < N) deg[i] = 0;
}

// ---------- prep: all weights -> bf16 transposed [n][k] ----------
__global__ void k_prep(const float* __restrict__ W1, const float* __restrict__ W2,
                       const float* __restrict__ Wq, const float* __restrict__ Wk,
                       const float* __restrict__ Wv, const float* __restrict__ Wo,
                       short* __restrict__ Wt1, short* __restrict__ Wt2,
                       short* __restrict__ Wtq, short* __restrict__ Wtk,
                       short* __restrict__ Wtv, short* __restrict__ Wto) {
    int i = blockIdx.x * 256 + threadIdx.x;     // 65536 threads
    {   int n = i >> 7, k = i & 127; Wt1[i] = f2b(W1[k * HID + n]); }
    {   int n = i >> 9, k = i & 511; Wt2[i] = f2b(W2[k * D + n]); }
    if (i < D * D) {
        int n = i >> 7, k = i & 127;
        Wtq[i] = f2b(Wq[k * D + n]);
        Wtk[i] = f2b(Wk[k * D + n]);
        Wtv[i] = f2b(Wv[k * D + n]);
        Wto[i] = f2b(Wo[k * D + n]);
    }
}

// ---------- K1 (MFMA): q fp32, kv fp8 interleaved ----------
__global__ __launch_bounds__(256) void k1_qkv_mfma(
        const float* __restrict__ x,
        const short* __restrict__ Wtq, const float* __restrict__ bq,
        const short* __restrict__ Wtk, const float* __restrict__ bk,
        const short* __restrict__ Wtv, const float* __restrict__ bv,
        float* __restrict__ q, unsigned char* __restrict__ kv, int N) {
    __shared__ short xs[MT * XP];
    __shared__ unsigned char kvs[MT * KVB];
    int m0 = blockIdx.x * MT;
    int t = threadIdx.x;
    int wave = t >> 6, lane = t & 63, quad = lane >> 4, l16 = lane & 15;

    {
        int row = t >> 3, c0 = (t & 7) * 16;
        int n = m0 + row;
        #pragma unroll
        for (int c = 0; c < 16; c += 4) {
            float4 xv = {0.f, 0.f, 0.f, 0.f};
            if (n < N) xv = *(const float4*)(x + (size_t)n * D + c0 + c);
            xs[row * XP + c0 + c + 0] = f2b(xv.x);
            xs[row * XP + c0 + c + 1] = f2b(xv.y);
            xs[row * XP + c0 + c + 2] = f2b(xv.z);
            xs[row * XP + c0 + c + 3] = f2b(xv.w);
        }
    }
    __syncthreads();

    f32x4 accq[2][2], acck[2][2], accv[2][2];
    #pragma unroll
    for (int nt = 0; nt < 2; ++nt) {
        int c = wave * 32 + nt * 16 + l16;
        float q0 = bq[c], k0 = bk[c], v0 = bv[c];
        #pragma unroll
        for (int mt = 0; mt < 2; ++mt) {
            accq[mt][nt] = (f32x4){q0, q0, q0, q0};
            acck[mt][nt] = (f32x4){k0, k0, k0, k0};
            accv[mt][nt] = (f32x4){v0, v0, v0, v0};
        }
    }
    #pragma unroll
    for (int kt = 0; kt < 4; ++kt) {
        int klane = kt * 32 + quad * 8;
        bf16x8 a0 = *(const bf16x8*)(xs + (l16)      * XP + klane);
        bf16x8 a1 = *(const bf16x8*)(xs + (16 + l16) * XP + klane);
        #pragma unroll
        for (int nt = 0; nt < 2; ++nt) {
            int c = wave * 32 + nt * 16 + l16;
            bf16x8 fq = *(const bf16x8*)(Wtq + (size_t)c * D + klane);
            bf16x8 fk = *(const bf16x8*)(Wtk + (size_t)c * D + klane);
            bf16x8 fv = *(const bf16x8*)(Wtv + (size_t)c * D + klane);
            accq[0][nt] = __builtin_amdgcn_mfma_f32_16x16x32_bf16(a0, fq, accq[0][nt], 0, 0, 0);
            accq[1][nt] = __builtin_amdgcn_mfma_f32_16x16x32_bf16(a1, fq, accq[1][nt], 0, 0, 0);
            acck[0][nt] = __builtin_amdgcn_mfma_f32_16x16x32_bf16(a0, fk, acck[0][nt], 0, 0, 0);
            acck[1][nt] = __builtin_amdgcn_mfma_f32_16x16x32_bf16(a1, fk, acck[1][nt], 0, 0, 0);
            accv[0][nt] = __builtin_amdgcn_mfma_f32_16x16x32_bf16(a0, fv, accv[0][nt], 0, 0, 0);
            accv[1][nt] = __builtin_amdgcn_mfma_f32_16x16x32_bf16(a1, fv, accv[1][nt], 0, 0, 0);
        }
    }
    #pragma unroll
    for (int mt = 0; mt < 2; ++mt)
        #pragma unroll
        for (int nt = 0; nt < 2; ++nt)
            #pragma unroll
            for (int r = 0; r < 4; ++r) {
                int row = mt * 16 + quad * 4 + r;
                int n = m0 + row;
                int c = wave * 32 + nt * 16 + l16;
                if (n < N) q[(size_t)n * D + c] = accq[mt][nt][r];
                int base = row * KVB + (c >> 1) * 4 + (c & 1);
                kvs[base]     = f2fp8(acck[mt][nt][r]);
                kvs[base + 2] = f2fp8(accv[mt][nt][r]);
            }
    __syncthreads();
    {   // coop write-out: 8 threads per row, 32 B each
        int row = t >> 3, c0 = (t & 7) * 32;
        int n = m0 + row;
        if (n < N) {
            *(uint4*)(kv + (size_t)n * 256 + c0) =
                *(const uint4*)(kvs + row * KVB + c0);
            *(uint4*)(kv + (size_t)n * 256 + c0 + 16) =
                *(const uint4*)(kvs + row * KVB + c0 + 16);
        }
    }
}

// ---------- CSR build ----------
__global__ void k_hist(const int* __restrict__ dst, int* __restrict__ deg, int E) {
    int i = blockIdx.x * blockDim.x + threadIdx.x;
    if (i < E) atomicAdd(&deg[dst[i]], 1);
}

__global__ void k_scan1(const int* __restrict__ deg, int* __restrict__ partial, int N) {
    __shared__ int red[256];
    int b = blockIdx.x, t = threadIdx.x;
    int base = b * SCB + t * 4;
    int s = 0;
    #pragma unroll
    for (int i = 0; i < 4; ++i) { int idx = base + i; if (idx < N) s += deg[idx]; }
    red[t] = s;
    __syncthreads();
    for (int off = 128; off > 0; off >>= 1) {
        if (t < off) red[t] += red[t + off];
        __syncthreads();
    }
    if (t == 0) partial[b] = red[0];
}

__global__ void k_scan2(int* __restrict__ partial, int nb) {
    __shared__ int s[256];
    int t = threadIdx.x;
    int v0 = (t < nb) ? partial[t] : 0;
    s[t] = v0;
    __syncthreads();
    for (int off = 1; off < 256; off <<= 1) {
        int v = (t >= off) ? s[t - off] : 0;
        __syncthreads();
        s[t] += v;
        __syncthreads();
    }
    if (t < nb) partial[t] = s[t] - v0;
    if (t == nb - 1) partial[nb] = s[t];
}

__global__ void k_scan3(const int* __restrict__ deg, const int* __restrict__ partial,
                        int* __restrict__ row_ptr, int* __restrict__ cursor,
                        int N, int nb) {
    __shared__ int red[256];
    int b = blockIdx.x, t = threadIdx.x;
    int base = b * SCB + t * 4;
    int d0[4]; int s = 0;
    #pragma unroll
    for (int i = 0; i < 4; ++i) {
        int idx = base + i;
        d0[i] = (idx < N) ? deg[idx] : 0;
        s += d0[i];
    }
    red[t] = s;
    __syncthreads();
    for (int off = 1; off < 256; off <<= 1) {
        int v = (t >= off) ? red[t - off] : 0;
        __syncthreads();
        red[t] += v;
        __syncthreads();
    }
    int off0 = partial[b] + red[t] - s;
    #pragma unroll
    for (int i = 0; i < 4; ++i) {
        int idx = base + i;
        if (idx < N) { row_ptr[idx] = off0; cursor[idx] = off0; off0 += d0[i]; }
    }
    if (b == 0 && t == 0) row_ptr[N] = partial[nb];
}

__global__ void k_scatter(const int* __restrict__ src, const int* __restrict__ dst,
                          int* __restrict__ cursor, int* __restrict__ col, int E) {
    int i = blockIdx.x * blockDim.x + threadIdx.x;
    if (i < E) {
        int d = dst[i];
        int pos = atomicAdd(&cursor[d], 1);
        col[pos] = src[i];
    }
}

// ---------- fused attention: fp8 kv gather, no-max softmax (|score| < 1) ----------
__global__ void k_attn(const float* __restrict__ q, const unsigned char* __restrict__ kv,
                       const int* __restrict__ row_ptr, const int* __restrict__ col,
                       float* __restrict__ agg, int N) {
    int wave = threadIdx.x >> 6;
    int lane = threadIdx.x & 63;
    int n = blockIdx.x * WPB + wave;
    if (n >= N) return;
    int beg = row_ptr[n], end = row_ptr[n + 1];

    float2 qv = *(const float2*)(q + (size_t)n * D + 2 * lane);

    float l = 0.f;
    float2 acc = {0.f, 0.f};

    unsigned pk_cur = 0;
    int sB = 0;
    if (beg < end) {
        int sA = col[beg];
        pk_cur = *(const unsigned*)(kv + (size_t)sA * 256 + 4 * lane);
    }
    if (beg + 1 < end) sB = col[beg + 1];

    for (int p = beg; p < end; ++p) {
        unsigned pk = pk_cur;
        int sC = (p + 2 < end) ? col[p + 2] : 0;       // col prefetch depth-2
        if (p + 1 < end)
            pk_cur = *(const unsigned*)(kv + (size_t)sB * 256 + 4 * lane);
        sB = sC;

        f32x2 kp = __builtin_amdgcn_cvt_pk_f32_fp8((int)pk, false);
        f32x2 vp = __builtin_amdgcn_cvt_pk_f32_fp8((int)pk, true);
        float part = qv.x * kp.x + qv.y * kp.y;
        part += __shfl_xor(part, 1);
        part += __shfl_xor(part, 2);
        part += __shfl_xor(part, 4);
        part += __shfl_xor(part, 8);                    // 16-lane head reduce
        float pe = __expf(part * 0.17677669529663687f); // scores bounded: no max needed
        l += pe;
        acc.x = fmaf(pe, vp.x, acc.x);
        acc.y = fmaf(pe, vp.y, acc.y);
    }
    float inv = (l > 0.f) ? 1.f / l : 0.f;
    float2 o = {acc.x * inv, acc.y * inv};
    *(float2*)(agg + (size_t)n * D + 2 * lane) = o;
}

// ---------- K56 (fused MFMA, occupancy-tuned): ----------
// ln kept in REGISTERS (fragment indexing of phase A == final store); stats via
// shfl + 32x4 LDS; hidden processed in two 256-col halves -> LDS ~27 KB.
__global__ __launch_bounds__(256) void k56_wo_ln_mlp(
        const float* __restrict__ agg, const short* __restrict__ Wto,
        const float* __restrict__ bo, const float* __restrict__ x,
        const float* __restrict__ g, const float* __restrict__ b,
        const short* __restrict__ Wt1, const float* __restrict__ b1,
        const short* __restrict__ Wt2, const float* __restrict__ b2,
        float* __restrict__ out, int N) {
    __shared__ short xs[MT * XP];            // 8704 B: agg tile, then ln tile (bf16)
    __shared__ short hid[MT * HHP];          // 16896 B: half-hidden (bf16)
    __shared__ float ps[MT * 4], ps2[MT * 4];// 2 KB: per-row per-wave partial sums
    int m0 = blockIdx.x * MT;
    int t = threadIdx.x;
    int wave = t >> 6, lane = t & 63, quad = lane >> 4, l16 = lane & 15;

    // stage agg -> xs bf16
    {
        int row = t >> 3, c0 = (t & 7) * 16;
        int n = m0 + row;
        #pragma unroll
        for (int c = 0; c < 16; c += 4) {
            float4 xv = {0.f, 0.f, 0.f, 0.f};
            if (n < N) xv = *(const float4*)(agg + (size_t)n * D + c0 + c);
            xs[row * XP + c0 + c + 0] = f2b(xv.x);
            xs[row * XP + c0 + c + 1] = f2b(xv.y);
            xs[row * XP + c0 + c + 2] = f2b(xv.z);
            xs[row * XP + c0 + c + 3] = f2b(xv.w);
        }
    }
    __syncthreads();

    // phase A: Wo GEMM + residual -> lnval registers
    f32x4 acc[2][2];
    #pragma unroll
    for (int nt = 0; nt < 2; ++nt) {
        float bb = bo[wave * 32 + nt * 16 + l16];
        acc[0][nt] = (f32x4){bb, bb, bb, bb};
        acc[1][nt] = (f32x4){bb, bb, bb, bb};
    }
    #pragma unroll
    for (int kt = 0; kt < 4; ++kt) {
        int klane = kt * 32 + quad * 8;
        bf16x8 a0 = *(const bf16x8*)(xs + (l16)      * XP + klane);
        bf16x8 a1 = *(const bf16x8*)(xs + (16 + l16) * XP + klane);
        #pragma unroll
        for (int nt = 0; nt < 2; ++nt) {
            bf16x8 bf = *(const bf16x8*)(Wto + (size_t)(wave * 32 + nt * 16 + l16) * D + klane);
            acc[0][nt] = __builtin_amdgcn_mfma_f32_16x16x32_bf16(a0, bf, acc[0][nt], 0, 0, 0);
            acc[1][nt] = __builtin_amdgcn_mfma_f32_16x16x32_bf16(a1, bf, acc[1][nt], 0, 0, 0);
        }
    }
    float lnval[2][2][4];
    #pragma unroll
    for (int mt = 0; mt < 2; ++mt)
        #pragma unroll
        for (int nt = 0; nt < 2; ++nt)
            #pragma unroll
            for (int r = 0; r < 4; ++r) {
                int n = m0 + mt * 16 + quad * 4 + r;
                int c = wave * 32 + nt * 16 + l16;
                float v = acc[mt][nt][r];
                if (n < N) v += x[(size_t)n * D + c];
                lnval[mt][nt][r] = v;
            }

    // LN stats: per-row partial over this thread's 2 cols, shfl over l16, LDS over waves
    #pragma unroll
    for (int mt = 0; mt < 2; ++mt)
        #pragma unroll
        for (int r = 0; r < 4; ++r) {
            float a0 = lnval[mt][0][r], a1 = lnval[mt][1][r];
            float s1 = a0 + a1;
            float s2 = a0 * a0 + a1 * a1;
            #pragma unroll
            for (int m = 1; m <= 8; m <<= 1) {
                s1 += __shfl_xor(s1, m);
                s2 += __shfl_xor(s2, m);
            }
            if (l16 == 0) {
                int row = mt * 16 + quad * 4 + r;
                ps[row * 4 + wave] = s1;
                ps2[row * 4 + wave] = s2;
            }
        }
    __syncthreads();

    // apply LN (per-thread rows), write bf16 ln tile to xs
    #pragma unroll
    for (int mt = 0; mt < 2; ++mt)
        #pragma unroll
        for (int r = 0; r < 4; ++r) {
            int row = mt * 16 + quad * 4 + r;
            float4 p1 = *(const float4*)(ps + row * 4);
            float4 p2 = *(const float4*)(ps2 + row * 4);
            float mm = (p1.x + p1.y + p1.z + p1.w) * (1.0f / D);
            float m2 = (p2.x + p2.y + p2.z + p2.w) * (1.0f / D);
            float rs = rsqrtf(m2 - mm * mm + 1e-5f);
            #pragma unroll
            for (int nt = 0; nt < 2; ++nt) {
                int c = wave * 32 + nt * 16 + l16;
                float v = (lnval[mt][nt][r] - mm) * rs * g[c] + b[c];
                lnval[mt][nt][r] = v;
                xs[row * XP + c] = f2b(v);
            }
        }
    __syncthreads();

    // MLP in two 256-col hidden halves
    f32x4 acc2[2][2];
    #pragma unroll
    for (int nt = 0; nt < 2; ++nt) {
        float bb = b2[wave * 32 + nt * 16 + l16];
        acc2[0][nt] = (f32x4){bb, bb, bb, bb};
        acc2[1][nt] = (f32x4){bb, bb, bb, bb};
    }
    #pragma unroll
    for (int h = 0; h < 2; ++h) {
        // B1: hidden cols [h*256 + wave*64, +64) for this wave
        f32x4 acc1[2][4];
        #pragma unroll
        for (int nt = 0; nt < 4; ++nt) {
            float bb = b1[h * 256 + wave * 64 + nt * 16 + l16];
            acc1[0][nt] = (f32x4){bb, bb, bb, bb};
            acc1[1][nt] = (f32x4){bb, bb, bb, bb};
        }
        #pragma unroll
        for (int kt = 0; kt < 4; ++kt) {
            int klane = kt * 32 + quad * 8;
            bf16x8 a0 = *(const bf16x8*)(xs + (l16)      * XP + klane);
            bf16x8 a1 = *(const bf16x8*)(xs + (16 + l16) * XP + klane);
            #pragma unroll
            for (int nt = 0; nt < 4; ++nt) {
                int hc = h * 256 + wave * 64 + nt * 16 + l16;
                bf16x8 bf = *(const bf16x8*)(Wt1 + (size_t)hc * D + klane);
                acc1[0][nt] = __builtin_amdgcn_mfma_f32_16x16x32_bf16(a0, bf, acc1[0][nt], 0, 0, 0);
                acc1[1][nt] = __builtin_amdgcn_mfma_f32_16x16x32_bf16(a1, bf, acc1[1][nt], 0, 0, 0);
            }
        }
        __syncthreads();   // all waves done reading hid of previous half
        #pragma unroll
        for (int mt = 0; mt < 2; ++mt)
            #pragma unroll
            for (int nt = 0; nt < 4; ++nt)
                #pragma unroll
                for (int r = 0; r < 4; ++r) {
                    int row = mt * 16 + quad * 4 + r;
                    int lc = wave * 64 + nt * 16 + l16;
                    hid[row * HHP + lc] = f2b(gelu_tanh(acc1[mt][nt][r]));
                }
        __syncthreads();   // half-hidden ready
        // B2 partial: K range [h*256, h*256+256)
        #pragma unroll
        for (int kt = 0; kt < 8; ++kt) {
            int klane = kt * 32 + quad * 8;
            bf16x8 a0 = *(const bf16x8*)(hid + (l16)      * HHP + klane);
            bf16x8 a1 = *(const bf16x8*)(hid + (16 + l16) * HHP + klane);
            #pragma unroll
            for (int nt = 0; nt < 2; ++nt) {
                bf16x8 bf = *(const bf16x8*)(Wt2 + (size_t)(wave * 32 + nt * 16 + l16) * HID
                                             + h * 256 + klane);
                acc2[0][nt] = __builtin_amdgcn_mfma_f32_16x16x32_bf16(a0, bf, acc2[0][nt], 0, 0, 0);
                acc2[1][nt] = __builtin_amdgcn_mfma_f32_16x16x32_bf16(a1, bf, acc2[1][nt], 0, 0, 0);
            }
        }
    }

    // final store: out = ln (fp32 regs) + mlp
    #pragma unroll
    for (int mt = 0; mt < 2; ++mt)
        #pragma unroll
        for (int nt = 0; nt < 2; ++nt)
            #pragma unroll
            for (int r = 0; r < 4; ++r) {
                int n = m0 + mt * 16 + quad * 4 + r;
                int c = wave * 32 + nt * 16 + l16;
                if (n < N)
                    out[(size_t)n * D + c] = lnval[mt][nt][r] + acc2[mt][nt][r];
            }
}

// ---------- launch ----------
extern "C" void kernel_launch(void* const* d_in, const int* in_sizes, int n_in,
                              void* d_out, int out_size, void* d_ws, size_t ws_size,
                              hipStream_t stream) {
    const float* x   = (const float*)d_in[0];
    const int*   ei  = (const int*)d_in[1];
    const float* Wq  = (const float*)d_in[2];
    const float* bq  = (const float*)d_in[3];
    const float* Wk  = (const float*)d_in[4];
    const float* bk  = (const float*)d_in[5];
    const float* Wv  = (const float*)d_in[6];
    const float* bv  = (const float*)d_in[7];
    const float* Wo  = (const float*)d_in[8];
    const float* bo  = (const float*)d_in[9];
    const float* lng = (const float*)d_in[10];
    const float* lnb = (const float*)d_in[11];
    const float* W1  = (const float*)d_in[12];
    const float* b1  = (const float*)d_in[13];
    const float* W2  = (const float*)d_in[14];
    const float* b2  = (const float*)d_in[15];
    float* out = (float*)d_out;

    int N = in_sizes[0] / D;
    int E = in_sizes[1] / 2;
    const int* srcp = ei;
    const int* dstp = ei + E;

    // workspace layout
    short* Wt1 = (short*)d_ws;                 // 512*128
    short* Wt2 = Wt1 + 512 * 128;              // 128*512
    short* Wtq = Wt2 + 512 * 128;              // 128*128
    short* Wtk = Wtq + 128 * 128;
    short* Wtv = Wtk + 128 * 128;
    short* Wto = Wtv + 128 * 128;
    float* q   = (float*)(Wto + 128 * 128);    // N*D fp32
    unsigned char* kv = (unsigned char*)(q + (size_t)N * D);  // N*256 bytes fp8
    float* agg = (float*)(kv + (size_t)N * 256);
    int*   deg     = (int*)(agg + (size_t)N * D);
    int*   row_ptr = deg + N;                  // N+1
    int*   cursor  = row_ptr + N + 1;
    int*   col     = cursor + N;               // E
    int*   partial = col + E;                  // nbs+1

    int nblk32 = (N + MT - 1) / MT;
    int eblk   = (E + 255) / 256;
    int nbs    = (N + SCB - 1) / SCB;

    k0_zero_deg<<<(N + 255) / 256, 256, 0, stream>>>(deg, N);
    k_prep<<<(512 * 128) / 256, 256, 0, stream>>>(W1, W2, Wq, Wk, Wv, Wo,
                                                  Wt1, Wt2, Wtq, Wtk, Wtv, Wto);
    k_hist<<<eblk, 256, 0, stream>>>(dstp, deg, E);
    k1_qkv_mfma<<<nblk32, 256, 0, stream>>>(x, Wtq, bq, Wtk, bk, Wtv, bv, q, kv, N);
    k_scan1<<<nbs, 256, 0, stream>>>(deg, partial, N);
    k_scan2<<<1, 256, 0, stream>>>(partial, nbs);
    k_scan3<<<nbs, 256, 0, stream>>>(deg, partial, row_ptr, cursor, N, nbs);
    k_scatter<<<eblk, 256, 0, stream>>>(srcp, dstp, cursor, col, E);
    k_attn<<<(N + WPB - 1) / WPB, WPB * 64, 0, stream>>>(q, kv, row_ptr, col, agg, N);
    k56_wo_ln_mlp<<<nblk32, 256, 0, stream>>>(agg, Wto, bo, x, lng, lnb,
                                              Wt1, b1, Wt2, b2, out, N);
}

// Round 8
// 277.356 us; speedup vs baseline: 3.0450x; 1.1439x over previous
//
#include <hip/hip_runtime.h>
#include <math.h>

#define D   128
#define HH  4
#define HD  32
#define HID 512
#define WPB 4     // nodes (waves) per block in fused attention
#define MT  32    // node tile for MFMA kernels
#define XP  136   // 128+8 padded LDS row (bf16 elems)
#define HHP 264   // 256+8 padded half-hidden row (bf16 elems)
#define KVB 264   // 256+8 padded kv LDS row (bytes)
#define SCB 1024  // elems per scan block

typedef __attribute__((ext_vector_type(8))) short bf16x8;  // 8 bf16 (4 VGPRs)
typedef __attribute__((ext_vector_type(4))) float f32x4;   // MFMA C/D frag
typedef __attribute__((ext_vector_type(2))) float f32x2;

// fp32 -> bf16 bits, round-to-nearest-even
__device__ __forceinline__ short f2b(float f) {
    unsigned u = __float_as_uint(f);
    unsigned r = (u + 0x7FFFu + ((u >> 16) & 1u)) >> 16;
    return (short)r;
}
// fp32 -> fp8 e4m3 (OCP on gfx950), via hw packed cvt
__device__ __forceinline__ unsigned char f2fp8(float f) {
    return (unsigned char)(__builtin_amdgcn_cvt_pk_fp8_f32(f, f, 0, false) & 0xFF);
}

// gelu tanh-approx via hw exp: 0.5x(1+tanh u) = x*e^{2u}/(e^{2u}+1)
__device__ __forceinline__ float gelu_tanh(float x) {
    float u = 0.7978845608028654f * (x + 0.044715f * x * x * x);
    float e = __expf(2.0f * u);
    return x * e * __builtin_amdgcn_rcpf(e + 1.0f);
}

// ---------- K0: zero degree array ----------
__global__ void k0_zero_deg(int* __restrict__ deg, int N) {
    int i = blockIdx.x * blockDim.x + threadIdx.x;
    if (i < N) deg[i] = 0;
}

// ---------- prep: all weights -> bf16 transposed [n][k] ----------
__global__ void k_prep(const float* __restrict__ W1, const float* __restrict__ W2,
                       const float* __restrict__ Wq, const float* __restrict__ Wk,
                       const float* __restrict__ Wv, const float* __restrict__ Wo,
                       short* __restrict__ Wt1, short* __restrict__ Wt2,
                       short* __restrict__ Wtq, short* __restrict__ Wtk,
                       short* __restrict__ Wtv, short* __restrict__ Wto) {
    int i = blockIdx.x * 256 + threadIdx.x;     // 65536 threads
    {   int n = i >> 7, k = i & 127; Wt1[i] = f2b(W1[k * HID + n]); }
    {   int n = i >> 9, k = i & 511; Wt2[i] = f2b(W2[k * D + n]); }
    if (i < D * D) {
        int n = i >> 7, k = i & 127;
        Wtq[i] = f2b(Wq[k * D + n]);
        Wtk[i] = f2b(Wk[k * D + n]);
        Wtv[i] = f2b(Wv[k * D + n]);
        Wto[i] = f2b(Wo[k * D + n]);
    }
}

// ---------- K1 (MFMA): q fp32, kv fp8 in 8-dim blocks ----------
// kv row (256 B): block j (j=0..15): bytes [16j,16j+8) = k[8j..8j+8),
//                                    bytes [16j+8,16j+16) = v[8j..8j+8)
__global__ __launch_bounds__(256) void k1_qkv_mfma(
        const float* __restrict__ x,
        const short* __restrict__ Wtq, const float* __restrict__ bq,
        const short* __restrict__ Wtk, const float* __restrict__ bk,
        const short* __restrict__ Wtv, const float* __restrict__ bv,
        float* __restrict__ q, unsigned char* __restrict__ kv, int N) {
    __shared__ short xs[MT * XP];
    __shared__ unsigned char kvs[MT * KVB];
    int m0 = blockIdx.x * MT;
    int t = threadIdx.x;
    int wave = t >> 6, lane = t & 63, quad = lane >> 4, l16 = lane & 15;

    {
        int row = t >> 3, c0 = (t & 7) * 16;
        int n = m0 + row;
        #pragma unroll
        for (int c = 0; c < 16; c += 4) {
            float4 xv = {0.f, 0.f, 0.f, 0.f};
            if (n < N) xv = *(const float4*)(x + (size_t)n * D + c0 + c);
            xs[row * XP + c0 + c + 0] = f2b(xv.x);
            xs[row * XP + c0 + c + 1] = f2b(xv.y);
            xs[row * XP + c0 + c + 2] = f2b(xv.z);
            xs[row * XP + c0 + c + 3] = f2b(xv.w);
        }
    }
    __syncthreads();

    f32x4 accq[2][2], acck[2][2], accv[2][2];
    #pragma unroll
    for (int nt = 0; nt < 2; ++nt) {
        int c = wave * 32 + nt * 16 + l16;
        float q0 = bq[c], k0 = bk[c], v0 = bv[c];
        #pragma unroll
        for (int mt = 0; mt < 2; ++mt) {
            accq[mt][nt] = (f32x4){q0, q0, q0, q0};
            acck[mt][nt] = (f32x4){k0, k0, k0, k0};
            accv[mt][nt] = (f32x4){v0, v0, v0, v0};
        }
    }
    #pragma unroll
    for (int kt = 0; kt < 4; ++kt) {
        int klane = kt * 32 + quad * 8;
        bf16x8 a0 = *(const bf16x8*)(xs + (l16)      * XP + klane);
        bf16x8 a1 = *(const bf16x8*)(xs + (16 + l16) * XP + klane);
        #pragma unroll
        for (int nt = 0; nt < 2; ++nt) {
            int c = wave * 32 + nt * 16 + l16;
            bf16x8 fq = *(const bf16x8*)(Wtq + (size_t)c * D + klane);
            bf16x8 fk = *(const bf16x8*)(Wtk + (size_t)c * D + klane);
            bf16x8 fv = *(const bf16x8*)(Wtv + (size_t)c * D + klane);
            accq[0][nt] = __builtin_amdgcn_mfma_f32_16x16x32_bf16(a0, fq, accq[0][nt], 0, 0, 0);
            accq[1][nt] = __builtin_amdgcn_mfma_f32_16x16x32_bf16(a1, fq, accq[1][nt], 0, 0, 0);
            acck[0][nt] = __builtin_amdgcn_mfma_f32_16x16x32_bf16(a0, fk, acck[0][nt], 0, 0, 0);
            acck[1][nt] = __builtin_amdgcn_mfma_f32_16x16x32_bf16(a1, fk, acck[1][nt], 0, 0, 0);
            accv[0][nt] = __builtin_amdgcn_mfma_f32_16x16x32_bf16(a0, fv, accv[0][nt], 0, 0, 0);
            accv[1][nt] = __builtin_amdgcn_mfma_f32_16x16x32_bf16(a1, fv, accv[1][nt], 0, 0, 0);
        }
    }
    #pragma unroll
    for (int mt = 0; mt < 2; ++mt)
        #pragma unroll
        for (int nt = 0; nt < 2; ++nt)
            #pragma unroll
            for (int r = 0; r < 4; ++r) {
                int row = mt * 16 + quad * 4 + r;
                int n = m0 + row;
                int c = wave * 32 + nt * 16 + l16;
                if (n < N) q[(size_t)n * D + c] = accq[mt][nt][r];
                int base = row * KVB + 16 * (c >> 3) + (c & 7);
                kvs[base]     = f2fp8(acck[mt][nt][r]);
                kvs[base + 8] = f2fp8(accv[mt][nt][r]);
            }
    __syncthreads();
    {   // coop write-out: 8 threads per row, 32 B each
        int row = t >> 3, c0 = (t & 7) * 32;
        int n = m0 + row;
        if (n < N) {
            *(uint4*)(kv + (size_t)n * 256 + c0) =
                *(const uint4*)(kvs + row * KVB + c0);
            *(uint4*)(kv + (size_t)n * 256 + c0 + 16) =
                *(const uint4*)(kvs + row * KVB + c0 + 16);
        }
    }
}

// ---------- CSR build ----------
__global__ void k_hist(const int* __restrict__ dst, int* __restrict__ deg, int E) {
    int i = blockIdx.x * blockDim.x + threadIdx.x;
    if (i < E) atomicAdd(&deg[dst[i]], 1);
}

__global__ void k_scan1(const int* __restrict__ deg, int* __restrict__ partial, int N) {
    __shared__ int red[256];
    int b = blockIdx.x, t = threadIdx.x;
    int base = b * SCB + t * 4;
    int s = 0;
    #pragma unroll
    for (int i = 0; i < 4; ++i) { int idx = base + i; if (idx < N) s += deg[idx]; }
    red[t] = s;
    __syncthreads();
    for (int off = 128; off > 0; off >>= 1) {
        if (t < off) red[t] += red[t + off];
        __syncthreads();
    }
    if (t == 0) partial[b] = red[0];
}

__global__ void k_scan2(int* __restrict__ partial, int nb) {
    __shared__ int s[256];
    int t = threadIdx.x;
    int v0 = (t < nb) ? partial[t] : 0;
    s[t] = v0;
    __syncthreads();
    for (int off = 1; off < 256; off <<= 1) {
        int v = (t >= off) ? s[t - off] : 0;
        __syncthreads();
        s[t] += v;
        __syncthreads();
    }
    if (t < nb) partial[t] = s[t] - v0;
    if (t == nb - 1) partial[nb] = s[t];
}

__global__ void k_scan3(const int* __restrict__ deg, const int* __restrict__ partial,
                        int* __restrict__ row_ptr, int* __restrict__ cursor,
                        int N, int nb) {
    __shared__ int red[256];
    int b = blockIdx.x, t = threadIdx.x;
    int base = b * SCB + t * 4;
    int d0[4]; int s = 0;
    #pragma unroll
    for (int i = 0; i < 4; ++i) {
        int idx = base + i;
        d0[i] = (idx < N) ? deg[idx] : 0;
        s += d0[i];
    }
    red[t] = s;
    __syncthreads();
    for (int off = 1; off < 256; off <<= 1) {
        int v = (t >= off) ? red[t - off] : 0;
        __syncthreads();
        red[t] += v;
        __syncthreads();
    }
    int off0 = partial[b] + red[t] - s;
    #pragma unroll
    for (int i = 0; i < 4; ++i) {
        int idx = base + i;
        if (idx < N) { row_ptr[idx] = off0; cursor[idx] = off0; off0 += d0[i]; }
    }
    if (b == 0 && t == 0) row_ptr[N] = partial[nb];
}

__global__ void k_scatter(const int* __restrict__ src, const int* __restrict__ dst,
                          int* __restrict__ cursor, int* __restrict__ col, int E) {
    int i = blockIdx.x * blockDim.x + threadIdx.x;
    if (i < E) {
        int d = dst[i];
        int pos = atomicAdd(&cursor[d], 1);
        col[pos] = src[i];
    }
}

// ---------- fused attention: 4 edges/iteration ----------
// lane = g*16 + s: g = edge slot (0..3), s = dim-block (dims [8s,8s+8)), head = s>>2.
// Per iteration each lane gathers 16 B (k8+v8 of its dim-block for its slot's edge).
// In-head dot reduce: shfl_xor 1,2 (4 lanes/head). Cross-slot reduce at end: shfl 16,32.
__global__ void k_attn(const float* __restrict__ q, const unsigned char* __restrict__ kv,
                       const int* __restrict__ row_ptr, const int* __restrict__ col,
                       float* __restrict__ agg, int N) {
    int wave = threadIdx.x >> 6;
    int lane = threadIdx.x & 63;
    int g = lane >> 4, s = lane & 15;
    int n = blockIdx.x * WPB + wave;
    if (n >= N) return;
    int beg = row_ptr[n], end = row_ptr[n + 1];

    float4 qa = *(const float4*)(q + (size_t)n * D + 8 * s);
    float4 qb = *(const float4*)(q + (size_t)n * D + 8 * s + 4);

    float acc[8] = {0.f, 0.f, 0.f, 0.f, 0.f, 0.f, 0.f, 0.f};
    float l = 0.f;

    int np = (end - beg + 3) >> 2;
    uint4 pk_cur = {0, 0, 0, 0};
    int idx_next = 0;
    if (np > 0) {
        int c0 = col[min(beg + g, end - 1)];
        pk_cur = *(const uint4*)(kv + (size_t)c0 * 256 + 16 * s);
        if (np > 1) idx_next = col[min(beg + 4 + g, end - 1)];
    }
    for (int it = 0; it < np; ++it) {
        uint4 pk = pk_cur;
        bool valid = (beg + it * 4 + g) < end;
        if (it + 1 < np) {                  // prefetch next iteration's kv + next-next col
            pk_cur = *(const uint4*)(kv + (size_t)idx_next * 256 + 16 * s);
            if (it + 2 < np)
                idx_next = col[min(beg + (it + 2) * 4 + g, end - 1)];
        }
        f32x2 k01 = __builtin_amdgcn_cvt_pk_f32_fp8((int)pk.x, false);
        f32x2 k23 = __builtin_amdgcn_cvt_pk_f32_fp8((int)pk.x, true);
        f32x2 k45 = __builtin_amdgcn_cvt_pk_f32_fp8((int)pk.y, false);
        f32x2 k67 = __builtin_amdgcn_cvt_pk_f32_fp8((int)pk.y, true);
        f32x2 v01 = __builtin_amdgcn_cvt_pk_f32_fp8((int)pk.z, false);
        f32x2 v23 = __builtin_amdgcn_cvt_pk_f32_fp8((int)pk.z, true);
        f32x2 v45 = __builtin_amdgcn_cvt_pk_f32_fp8((int)pk.w, false);
        f32x2 v67 = __builtin_amdgcn_cvt_pk_f32_fp8((int)pk.w, true);
        float d = qa.x * k01.x + qa.y * k01.y + qa.z * k23.x + qa.w * k23.y
                + qb.x * k45.x + qb.y * k45.y + qb.z * k67.x + qb.w * k67.y;
        d += __shfl_xor(d, 1);
        d += __shfl_xor(d, 2);              // head dot complete (4 lanes/head)
        float pe = __expf(d * 0.17677669529663687f);
        pe = valid ? pe : 0.f;
        l += pe;
        acc[0] = fmaf(pe, v01.x, acc[0]);
        acc[1] = fmaf(pe, v01.y, acc[1]);
        acc[2] = fmaf(pe, v23.x, acc[2]);
        acc[3] = fmaf(pe, v23.y, acc[3]);
        acc[4] = fmaf(pe, v45.x, acc[4]);
        acc[5] = fmaf(pe, v45.y, acc[5]);
        acc[6] = fmaf(pe, v67.x, acc[6]);
        acc[7] = fmaf(pe, v67.y, acc[7]);
    }
    // cross-slot reduce (g dimension)
    #pragma unroll
    for (int m = 16; m <= 32; m <<= 1) {
        l += __shfl_xor(l, m);
        #pragma unroll
        for (int i = 0; i < 8; ++i) acc[i] += __shfl_xor(acc[i], m);
    }
    if (g == 0) {
        float inv = (l > 0.f) ? 1.f / l : 0.f;
        float4 o1 = {acc[0] * inv, acc[1] * inv, acc[2] * inv, acc[3] * inv};
        float4 o2 = {acc[4] * inv, acc[5] * inv, acc[6] * inv, acc[7] * inv};
        *(float4*)(agg + (size_t)n * D + 8 * s)     = o1;
        *(float4*)(agg + (size_t)n * D + 8 * s + 4) = o2;
    }
}

// ---------- K56 (fused MFMA, occupancy-tuned) ----------
__global__ __launch_bounds__(256) void k56_wo_ln_mlp(
        const float* __restrict__ agg, const short* __restrict__ Wto,
        const float* __restrict__ bo, const float* __restrict__ x,
        const float* __restrict__ g, const float* __restrict__ b,
        const short* __restrict__ Wt1, const float* __restrict__ b1,
        const short* __restrict__ Wt2, const float* __restrict__ b2,
        float* __restrict__ out, int N) {
    __shared__ short xs[MT * XP];            // agg tile, then ln tile (bf16)
    __shared__ short hid[MT * HHP];          // half-hidden (bf16)
    __shared__ float ps[MT * 4], ps2[MT * 4];
    int m0 = blockIdx.x * MT;
    int t = threadIdx.x;
    int wave = t >> 6, lane = t & 63, quad = lane >> 4, l16 = lane & 15;

    {
        int row = t >> 3, c0 = (t & 7) * 16;
        int n = m0 + row;
        #pragma unroll
        for (int c = 0; c < 16; c += 4) {
            float4 xv = {0.f, 0.f, 0.f, 0.f};
            if (n < N) xv = *(const float4*)(agg + (size_t)n * D + c0 + c);
            xs[row * XP + c0 + c + 0] = f2b(xv.x);
            xs[row * XP + c0 + c + 1] = f2b(xv.y);
            xs[row * XP + c0 + c + 2] = f2b(xv.z);
            xs[row * XP + c0 + c + 3] = f2b(xv.w);
        }
    }
    __syncthreads();

    f32x4 acc[2][2];
    #pragma unroll
    for (int nt = 0; nt < 2; ++nt) {
        float bb = bo[wave * 32 + nt * 16 + l16];
        acc[0][nt] = (f32x4){bb, bb, bb, bb};
        acc[1][nt] = (f32x4){bb, bb, bb, bb};
    }
    #pragma unroll
    for (int kt = 0; kt < 4; ++kt) {
        int klane = kt * 32 + quad * 8;
        bf16x8 a0 = *(const bf16x8*)(xs + (l16)      * XP + klane);
        bf16x8 a1 = *(const bf16x8*)(xs + (16 + l16) * XP + klane);
        #pragma unroll
        for (int nt = 0; nt < 2; ++nt) {
            bf16x8 bf = *(const bf16x8*)(Wto + (size_t)(wave * 32 + nt * 16 + l16) * D + klane);
            acc[0][nt] = __builtin_amdgcn_mfma_f32_16x16x32_bf16(a0, bf, acc[0][nt], 0, 0, 0);
            acc[1][nt] = __builtin_amdgcn_mfma_f32_16x16x32_bf16(a1, bf, acc[1][nt], 0, 0, 0);
        }
    }
    float lnval[2][2][4];
    #pragma unroll
    for (int mt = 0; mt < 2; ++mt)
        #pragma unroll
        for (int nt = 0; nt < 2; ++nt)
            #pragma unroll
            for (int r = 0; r < 4; ++r) {
                int n = m0 + mt * 16 + quad * 4 + r;
                int c = wave * 32 + nt * 16 + l16;
                float v = acc[mt][nt][r];
                if (n < N) v += x[(size_t)n * D + c];
                lnval[mt][nt][r] = v;
            }

    #pragma unroll
    for (int mt = 0; mt < 2; ++mt)
        #pragma unroll
        for (int r = 0; r < 4; ++r) {
            float a0 = lnval[mt][0][r], a1 = lnval[mt][1][r];
            float s1 = a0 + a1;
            float s2 = a0 * a0 + a1 * a1;
            #pragma unroll
            for (int m = 1; m <= 8; m <<= 1) {
                s1 += __shfl_xor(s1, m);
                s2 += __shfl_xor(s2, m);
            }
            if (l16 == 0) {
                int row = mt * 16 + quad * 4 + r;
                ps[row * 4 + wave] = s1;
                ps2[row * 4 + wave] = s2;
            }
        }
    __syncthreads();

    #pragma unroll
    for (int mt = 0; mt < 2; ++mt)
        #pragma unroll
        for (int r = 0; r < 4; ++r) {
            int row = mt * 16 + quad * 4 + r;
            float4 p1 = *(const float4*)(ps + row * 4);
            float4 p2 = *(const float4*)(ps2 + row * 4);
            float mm = (p1.x + p1.y + p1.z + p1.w) * (1.0f / D);
            float m2 = (p2.x + p2.y + p2.z + p2.w) * (1.0f / D);
            float rs = rsqrtf(m2 - mm * mm + 1e-5f);
            #pragma unroll
            for (int nt = 0; nt < 2; ++nt) {
                int c = wave * 32 + nt * 16 + l16;
                float v = (lnval[mt][nt][r] - mm) * rs * g[c] + b[c];
                lnval[mt][nt][r] = v;
                xs[row * XP + c] = f2b(v);
            }
        }
    __syncthreads();

    f32x4 acc2[2][2];
    #pragma unroll
    for (int nt = 0; nt < 2; ++nt) {
        float bb = b2[wave * 32 + nt * 16 + l16];
        acc2[0][nt] = (f32x4){bb, bb, bb, bb};
        acc2[1][nt] = (f32x4){bb, bb, bb, bb};
    }
    #pragma unroll
    for (int h = 0; h < 2; ++h) {
        f32x4 acc1[2][4];
        #pragma unroll
        for (int nt = 0; nt < 4; ++nt) {
            float bb = b1[h * 256 + wave * 64 + nt * 16 + l16];
            acc1[0][nt] = (f32x4){bb, bb, bb, bb};
            acc1[1][nt] = (f32x4){bb, bb, bb, bb};
        }
        #pragma unroll
        for (int kt = 0; kt < 4; ++kt) {
            int klane = kt * 32 + quad * 8;
            bf16x8 a0 = *(const bf16x8*)(xs + (l16)      * XP + klane);
            bf16x8 a1 = *(const bf16x8*)(xs + (16 + l16) * XP + klane);
            #pragma unroll
            for (int nt = 0; nt < 4; ++nt) {
                int hc = h * 256 + wave * 64 + nt * 16 + l16;
                bf16x8 bf = *(const bf16x8*)(Wt1 + (size_t)hc * D + klane);
                acc1[0][nt] = __builtin_amdgcn_mfma_f32_16x16x32_bf16(a0, bf, acc1[0][nt], 0, 0, 0);
                acc1[1][nt] = __builtin_amdgcn_mfma_f32_16x16x32_bf16(a1, bf, acc1[1][nt], 0, 0, 0);
            }
        }
        __syncthreads();
        #pragma unroll
        for (int mt = 0; mt < 2; ++mt)
            #pragma unroll
            for (int nt = 0; nt < 4; ++nt)
                #pragma unroll
                for (int r = 0; r < 4; ++r) {
                    int row = mt * 16 + quad * 4 + r;
                    int lc = wave * 64 + nt * 16 + l16;
                    hid[row * HHP + lc] = f2b(gelu_tanh(acc1[mt][nt][r]));
                }
        __syncthreads();
        #pragma unroll
        for (int kt = 0; kt < 8; ++kt) {
            int klane = kt * 32 + quad * 8;
            bf16x8 a0 = *(const bf16x8*)(hid + (l16)      * HHP + klane);
            bf16x8 a1 = *(const bf16x8*)(hid + (16 + l16) * HHP + klane);
            #pragma unroll
            for (int nt = 0; nt < 2; ++nt) {
                bf16x8 bf = *(const bf16x8*)(Wt2 + (size_t)(wave * 32 + nt * 16 + l16) * HID
                                             + h * 256 + klane);
                acc2[0][nt] = __builtin_amdgcn_mfma_f32_16x16x32_bf16(a0, bf, acc2[0][nt], 0, 0, 0);
                acc2[1][nt] = __builtin_amdgcn_mfma_f32_16x16x32_bf16(a1, bf, acc2[1][nt], 0, 0, 0);
            }
        }
    }

    #pragma unroll
    for (int mt = 0; mt < 2; ++mt)
        #pragma unroll
        for (int nt = 0; nt < 2; ++nt)
            #pragma unroll
            for (int r = 0; r < 4; ++r) {
                int n = m0 + mt * 16 + quad * 4 + r;
                int c = wave * 32 + nt * 16 + l16;
                if (n < N)
                    out[(size_t)n * D + c] = lnval[mt][nt][r] + acc2[mt][nt][r];
            }
}

// ---------- launch ----------
extern "C" void kernel_launch(void* const* d_in, const int* in_sizes, int n_in,
                              void* d_out, int out_size, void* d_ws, size_t ws_size,
                              hipStream_t stream) {
    const float* x   = (const float*)d_in[0];
    const int*   ei  = (const int*)d_in[1];
    const float* Wq  = (const float*)d_in[2];
    const float* bq  = (const float*)d_in[3];
    const float* Wk  = (const float*)d_in[4];
    const float* bk  = (const float*)d_in[5];
    const float* Wv  = (const float*)d_in[6];
    const float* bv  = (const float*)d_in[7];
    const float* Wo  = (const float*)d_in[8];
    const float* bo  = (const float*)d_in[9];
    const float* lng = (const float*)d_in[10];
    const float* lnb = (const float*)d_in[11];
    const float* W1  = (const float*)d_in[12];
    const float* b1  = (const float*)d_in[13];
    const float* W2  = (const float*)d_in[14];
    const float* b2  = (const float*)d_in[15];
    float* out = (float*)d_out;

    int N = in_sizes[0] / D;
    int E = in_sizes[1] / 2;
    const int* srcp = ei;
    const int* dstp = ei + E;

    // workspace layout
    short* Wt1 = (short*)d_ws;                 // 512*128
    short* Wt2 = Wt1 + 512 * 128;              // 128*512
    short* Wtq = Wt2 + 512 * 128;              // 128*128
    short* Wtk = Wtq + 128 * 128;
    short* Wtv = Wtk + 128 * 128;
    short* Wto = Wtv + 128 * 128;
    float* q   = (float*)(Wto + 128 * 128);    // N*D fp32
    unsigned char* kv = (unsigned char*)(q + (size_t)N * D);  // N*256 bytes fp8
    float* agg = (float*)(kv + (size_t)N * 256);
    int*   deg     = (int*)(agg + (size_t)N * D);
    int*   row_ptr = deg + N;                  // N+1
    int*   cursor  = row_ptr + N + 1;
    int*   col     = cursor + N;               // E
    int*   partial = col + E;                  // nbs+1

    int nblk32 = (N + MT - 1) / MT;
    int eblk   = (E + 255) / 256;
    int nbs    = (N + SCB - 1) / SCB;

    k0_zero_deg<<<(N + 255) / 256, 256, 0, stream>>>(deg, N);
    k_prep<<<(512 * 128) / 256, 256, 0, stream>>>(W1, W2, Wq, Wk, Wv, Wo,
                                                  Wt1, Wt2, Wtq, Wtk, Wtv, Wto);
    k_hist<<<eblk, 256, 0, stream>>>(dstp, deg, E);
    k1_qkv_mfma<<<nblk32, 256, 0, stream>>>(x, Wtq, bq, Wtk, bk, Wtv, bv, q, kv, N);
    k_scan1<<<nbs, 256, 0, stream>>>(deg, partial, N);
    k_scan2<<<1, 256, 0, stream>>>(partial, nbs);
    k_scan3<<<nbs, 256, 0, stream>>>(deg, partial, row_ptr, cursor, N, nbs);
    k_scatter<<<eblk, 256, 0, stream>>>(srcp, dstp, cursor, col, E);
    k_attn<<<(N + WPB - 1) / WPB, WPB * 64, 0, stream>>>(q, kv, row_ptr, col, agg, N);
    k56_wo_ln_mlp<<<nblk32, 256, 0, stream>>>(agg, Wto, bo, x, lng, lnb,
                                              Wt1, b1, Wt2, b2, out, N);
}